// Round 2
// baseline (357.596 us; speedup 1.0000x reference)
//
#include <hip/hip_runtime.h>
#include <hip/hip_fp16.h>

#define T_DIM 4096
#define D_DIM 1024

typedef _Float16 f16;
typedef _Float16 f16x4 __attribute__((ext_vector_type(4)));
typedef _Float16 f16x8 __attribute__((ext_vector_type(8)));
typedef float f32x4 __attribute__((ext_vector_type(4)));

#define GAS __attribute__((address_space(1)))
#define LAS __attribute__((address_space(3)))

// ---------------------------------------------------------------------------
// Preprocessing: fp32 -> fp16 hi/lo split (flat, vectorized x4)
// ---------------------------------------------------------------------------
__global__ void split4(const float* __restrict__ in, f16* __restrict__ hi,
                       f16* __restrict__ lo) {
    int i = (blockIdx.x * 256 + threadIdx.x) * 4;
    float4 v = *(const float4*)(in + i);
    float vv[4] = {v.x, v.y, v.z, v.w};
    f16x4 h, l;
#pragma unroll
    for (int j = 0; j < 4; ++j) {
        f16 hh = (f16)vv[j];
        h[j] = hh;
        l[j] = (f16)(vv[j] - (float)hh);
    }
    *(f16x4*)(hi + i) = h;
    *(f16x4*)(lo + i) = l;
}

// ---------------------------------------------------------------------------
// Preprocessing: transpose + split.  in [R][C] fp32 -> hi/lo [C][R] fp16
// ---------------------------------------------------------------------------
__global__ void transpose_split(const float* __restrict__ in, f16* __restrict__ hi,
                                f16* __restrict__ lo, int R, int C) {
    __shared__ float t[32][33];
    int tx = threadIdx.x & 31;
    int ty = threadIdx.x >> 5;  // 0..7
#pragma unroll
    for (int q = 0; q < 4; ++q) {
        int r = blockIdx.y * 32 + ty + q * 8;
        int c = blockIdx.x * 32 + tx;
        t[ty + q * 8][tx] = in[(size_t)r * C + c];
    }
    __syncthreads();
#pragma unroll
    for (int q = 0; q < 4; ++q) {
        int c = blockIdx.x * 32 + ty + q * 8;  // output row (= original col)
        int r = blockIdx.y * 32 + tx;          // output col (= original row)
        float v = t[tx][ty + q * 8];
        size_t idx = (size_t)c * R + r;
        f16 h = (f16)v;
        hi[idx] = h;
        lo[idx] = (f16)(v - (float)h);
    }
}

// ---------------------------------------------------------------------------
// Stage a 128x32 fp16 tile (row-major, ld = K) into LDS via global_load_lds.
// LDS layout: 512 slots of 16B; slot p = r*4 + c'' where the data is global
// chunk c = c'' ^ ((r>>1)&3)  (XOR swizzle applied on the GLOBAL source so the
// LDS destination stays linear — global_load_lds requirement).
// ---------------------------------------------------------------------------
__device__ __forceinline__ void stage128x32(const f16* __restrict__ src, int ld,
                                            f16* lds_tile, int w, int l) {
#pragma unroll
    for (int q = 0; q < 2; ++q) {
        int p = (w * 2 + q) * 64 + l;           // slot 0..511
        int r = p >> 2;                         // tile row 0..127
        int c = (p & 3) ^ ((r >> 1) & 3);       // swizzled global 16B chunk
        const f16* g = src + r * ld + c * 8;
        f16* d = lds_tile + (w * 2 + q) * 512;  // wave-uniform base
        __builtin_amdgcn_global_load_lds((const GAS void*)g, (LAS void*)d, 16, 0, 0);
    }
}

// ---------------------------------------------------------------------------
// Generic NT GEMM: C[M,N] = A[M,K] * B'[N,K]^T   (both operands fp16)
// SPLIT3: A,B given as hi/lo pairs; 3-pass MFMA for ~fp32 product accuracy.
// OUT_MODE: 0 = fp32 C, 1 = fp16 hi/lo split C, 2 = fp16 C.
// CAUSAL_SKIP: skip blocks strictly above the diagonal (gemm2).
// KCAP_CAUSAL: cap K at row0+128 (gemm3; A cols beyond are zero).
// 128x128 tile, BK=32, 256 threads = 4 waves in 2x2, each wave 64x64 out.
// ---------------------------------------------------------------------------
template <bool SPLIT3, int OUT_MODE, bool CAUSAL_SKIP, bool KCAP_CAUSAL>
__global__ __launch_bounds__(256) void gemm_nt(
    const f16* __restrict__ Ah, const f16* __restrict__ Al,
    const f16* __restrict__ Bh, const f16* __restrict__ Bl,
    float* __restrict__ Cf, f16* __restrict__ Ch, f16* __restrict__ Cl,
    int M, int N, int K) {
    const int row0 = blockIdx.y * 128;
    const int col0 = blockIdx.x * 128;
    if (CAUSAL_SKIP) {
        if (col0 > row0 + 127) return;  // wholly above diagonal: never read
    }
    int Keff = K;
    if (KCAP_CAUSAL) {
        Keff = row0 + 128;
        if (Keff > K) Keff = K;
    }

    __shared__ f16 lds[(SPLIT3 ? 4 : 2) * 128 * 32];
    f16* Ah_t = lds;
    f16* Bh_t = lds + 128 * 32;
    f16* Al_t = lds + 2 * 128 * 32;  // only used when SPLIT3
    f16* Bl_t = lds + 3 * 128 * 32;

    const int tid = threadIdx.x;
    const int w = tid >> 6, l = tid & 63;
    const int wm = w >> 1, wn = w & 1;
    const int lr = l & 15;   // row within 16x16 fragment
    const int kg = l >> 4;   // k-group (8 consecutive k per group)
    const int cswz = kg ^ ((lr >> 1) & 3);
    const int aoff = (wm * 64 + lr) * 32 + cswz * 8;
    const int boff = (wn * 64 + lr) * 32 + cswz * 8;

    const f16* Asrc = Ah + (size_t)row0 * K;
    const f16* Bsrc = Bh + (size_t)col0 * K;
    const f16* Asrc_l = SPLIT3 ? Al + (size_t)row0 * K : nullptr;
    const f16* Bsrc_l = SPLIT3 ? Bl + (size_t)col0 * K : nullptr;

    f32x4 acc[4][4] = {};

    for (int k0 = 0; k0 < Keff; k0 += 32) {
        __syncthreads();  // previous iteration's reads done before overwrite
        stage128x32(Asrc + k0, K, Ah_t, w, l);
        stage128x32(Bsrc + k0, K, Bh_t, w, l);
        if constexpr (SPLIT3) {
            stage128x32(Asrc_l + k0, K, Al_t, w, l);
            stage128x32(Bsrc_l + k0, K, Bl_t, w, l);
        }
        __syncthreads();  // compiler drains vmcnt(0) before barrier -> data ready

        f16x8 ah[4], bh[4], al[4], bl[4];
#pragma unroll
        for (int m = 0; m < 4; ++m) {
            ah[m] = *(const f16x8*)&Ah_t[aoff + m * 512];
            if constexpr (SPLIT3) al[m] = *(const f16x8*)&Al_t[aoff + m * 512];
        }
#pragma unroll
        for (int n = 0; n < 4; ++n) {
            bh[n] = *(const f16x8*)&Bh_t[boff + n * 512];
            if constexpr (SPLIT3) bl[n] = *(const f16x8*)&Bl_t[boff + n * 512];
        }
#pragma unroll
        for (int m = 0; m < 4; ++m)
#pragma unroll
            for (int n = 0; n < 4; ++n) {
                acc[m][n] = __builtin_amdgcn_mfma_f32_16x16x32_f16(ah[m], bh[n],
                                                                   acc[m][n], 0, 0, 0);
                if constexpr (SPLIT3) {
                    acc[m][n] = __builtin_amdgcn_mfma_f32_16x16x32_f16(
                        al[m], bh[n], acc[m][n], 0, 0, 0);
                    acc[m][n] = __builtin_amdgcn_mfma_f32_16x16x32_f16(
                        ah[m], bl[n], acc[m][n], 0, 0, 0);
                }
            }
    }

    // Epilogue. C/D layout: col = lane&15, row = (lane>>4)*4 + reg  [m89/m91]
#pragma unroll
    for (int m = 0; m < 4; ++m)
#pragma unroll
        for (int n = 0; n < 4; ++n)
#pragma unroll
            for (int j = 0; j < 4; ++j) {
                int row = row0 + wm * 64 + m * 16 + kg * 4 + j;
                int col = col0 + wn * 64 + n * 16 + lr;
                size_t idx = (size_t)row * N + col;
                float v = acc[m][n][j];
                if constexpr (OUT_MODE == 0) {
                    Cf[idx] = v;
                } else if constexpr (OUT_MODE == 1) {
                    f16 h = (f16)v;
                    Ch[idx] = h;
                    Cl[idx] = (f16)(v - (float)h);
                } else {
                    Ch[idx] = (f16)v;
                }
            }
}

// ---------------------------------------------------------------------------
// Causal row softmax: logits [T,T] fp32 -> attn [T,T] fp16.
// Row i uses cols 0..i; writes zeros for i < j < jmax (next 128 boundary,
// which is all gemm3 will ever read).
// ---------------------------------------------------------------------------
__global__ void softmax_causal(const float* __restrict__ L, f16* __restrict__ A) {
    const int i = blockIdx.x;
    const int n = i + 1;
    const int tid = threadIdx.x;  // 256 threads
    const float* row = L + (size_t)i * T_DIM;
    f16* arow = A + (size_t)i * T_DIM;

    float m = -INFINITY, s = 0.f;
    for (int j = tid; j < n; j += 256) {
        float v = row[j];
        if (v > m) {
            s = s * __expf(m - v) + 1.f;
            m = v;
        } else {
            s += __expf(v - m);
        }
    }

    __shared__ float sm[256], ss[256];
    sm[tid] = m;
    ss[tid] = s;
    __syncthreads();
    for (int o = 128; o > 0; o >>= 1) {
        if (tid < o) {
            float m1 = sm[tid], s1 = ss[tid];
            float m2 = sm[tid + o], s2 = ss[tid + o];
            float M = fmaxf(m1, m2);
            float S = (M == -INFINITY) ? 0.f
                                       : s1 * __expf(m1 - M) + s2 * __expf(m2 - M);
            sm[tid] = M;
            ss[tid] = S;
        }
        __syncthreads();
    }
    const float M = sm[0];
    const float inv = 1.f / ss[0];

    const int jmax = ((i >> 7) + 1) << 7;  // gemm3 reads cols < this
    for (int j = tid; j < jmax; j += 256) {
        float v = (j < n) ? __expf(row[j] - M) * inv : 0.f;
        arow[j] = (f16)v;
    }
}

// ---------------------------------------------------------------------------
extern "C" void kernel_launch(void* const* d_in, const int* in_sizes, int n_in,
                              void* d_out, int out_size, void* d_ws, size_t ws_size,
                              hipStream_t stream) {
    (void)in_sizes; (void)n_in; (void)out_size; (void)ws_size;
    const float* x = (const float*)d_in[0];
    const float* wqk = (const float*)d_in[1];
    const float* wov = (const float*)d_in[2];
    float* out = (float*)d_out;
    char* ws = (char*)d_ws;
    const size_t MB = 1024 * 1024;

    f16* x_hi    = (f16*)(ws + 0 * MB);    // 8 MB  [T][D]
    f16* x_lo    = (f16*)(ws + 8 * MB);    // 8 MB
    f16* wqkT_hi = (f16*)(ws + 16 * MB);   // 2 MB  [D][D] (= Wqk^T)
    f16* wqkT_lo = (f16*)(ws + 18 * MB);   // 2 MB
    f16* wovT_hi = (f16*)(ws + 20 * MB);   // 2 MB
    f16* wovT_lo = (f16*)(ws + 22 * MB);   // 2 MB
    f16* xT_hi   = (f16*)(ws + 24 * MB);   // 8 MB  [D][T]
    f16* xT_lo   = (f16*)(ws + 32 * MB);   // 8 MB (unused downstream)
    f16* q_hi    = (f16*)(ws + 40 * MB);   // 8 MB  [T][D]
    f16* q_lo    = (f16*)(ws + 48 * MB);   // 8 MB
    f16* z_hi    = (f16*)(ws + 56 * MB);   // 8 MB  [T][D]
    f16* attn    = (f16*)(ws + 64 * MB);   // 32 MB [T][T]
    float* logit = (float*)(ws + 96 * MB); // 64 MB [T][T]
    // total: 160 MB

    // 1) splits / transposes
    split4<<<(T_DIM * D_DIM) / 1024, 256, 0, stream>>>(x, x_hi, x_lo);
    transpose_split<<<dim3(D_DIM / 32, D_DIM / 32), 256, 0, stream>>>(
        wqk, wqkT_hi, wqkT_lo, D_DIM, D_DIM);
    transpose_split<<<dim3(D_DIM / 32, D_DIM / 32), 256, 0, stream>>>(
        wov, wovT_hi, wovT_lo, D_DIM, D_DIM);
    transpose_split<<<dim3(D_DIM / 32, T_DIM / 32), 256, 0, stream>>>(
        x, xT_hi, xT_lo, T_DIM, D_DIM);

    // 2) Q = x @ Wqk  (3-pass split in, fp16 hi/lo out)
    gemm_nt<true, 1, false, false>
        <<<dim3(D_DIM / 128, T_DIM / 128), 256, 0, stream>>>(
            x_hi, x_lo, wqkT_hi, wqkT_lo, nullptr, q_hi, q_lo, T_DIM, D_DIM, D_DIM);

    // 3) logits = Q @ x^T  (3-pass split, fp32 out, causal block skip)
    gemm_nt<true, 0, true, false>
        <<<dim3(T_DIM / 128, T_DIM / 128), 256, 0, stream>>>(
            q_hi, q_lo, x_hi, x_lo, logit, nullptr, nullptr, T_DIM, T_DIM, D_DIM);

    // 4) attn = causal softmax(logits)
    softmax_causal<<<T_DIM, 256, 0, stream>>>(logit, attn);

    // 5) z = attn @ x  (single-pass fp16, K capped at diagonal)
    gemm_nt<false, 2, false, true>
        <<<dim3(D_DIM / 128, T_DIM / 128), 256, 0, stream>>>(
            attn, nullptr, xT_hi, nullptr, nullptr, z_hi, nullptr, T_DIM, D_DIM, T_DIM);

    // 6) out = z @ Wov  (single-pass fp16, fp32 out)
    gemm_nt<false, 0, false, false>
        <<<dim3(D_DIM / 128, T_DIM / 128), 256, 0, stream>>>(
            z_hi, nullptr, wovT_hi, nullptr, out, nullptr, nullptr, T_DIM, D_DIM, D_DIM);
}

// Round 6
// 315.638 us; speedup vs baseline: 1.1329x; 1.1329x over previous
//
#include <hip/hip_runtime.h>
#include <hip/hip_fp16.h>

#define T_DIM 4096
#define D_DIM 1024

typedef _Float16 f16;
typedef _Float16 f16x4 __attribute__((ext_vector_type(4)));
typedef _Float16 f16x8 __attribute__((ext_vector_type(8)));
typedef float f32x4 __attribute__((ext_vector_type(4)));

#define GAS __attribute__((address_space(1)))
#define LAS __attribute__((address_space(3)))

// ---------------------------------------------------------------------------
// Preprocessing: fp32 -> fp16 hi/lo split (flat, vectorized x4)
// ---------------------------------------------------------------------------
__global__ void split4(const float* __restrict__ in, f16* __restrict__ hi,
                       f16* __restrict__ lo) {
    int i = (blockIdx.x * 256 + threadIdx.x) * 4;
    float4 v = *(const float4*)(in + i);
    float vv[4] = {v.x, v.y, v.z, v.w};
    f16x4 h, l;
#pragma unroll
    for (int j = 0; j < 4; ++j) {
        f16 hh = (f16)vv[j];
        h[j] = hh;
        l[j] = (f16)(vv[j] - (float)hh);
    }
    *(f16x4*)(hi + i) = h;
    *(f16x4*)(lo + i) = l;
}

// ---------------------------------------------------------------------------
// Preprocessing: transpose + split.  in [R][C] fp32 -> hi/lo [C][R] fp16
// ---------------------------------------------------------------------------
__global__ void transpose_split(const float* __restrict__ in, f16* __restrict__ hi,
                                f16* __restrict__ lo, int R, int C) {
    __shared__ float t[32][33];
    int tx = threadIdx.x & 31;
    int ty = threadIdx.x >> 5;  // 0..7
#pragma unroll
    for (int q = 0; q < 4; ++q) {
        int r = blockIdx.y * 32 + ty + q * 8;
        int c = blockIdx.x * 32 + tx;
        t[ty + q * 8][tx] = in[(size_t)r * C + c];
    }
    __syncthreads();
#pragma unroll
    for (int q = 0; q < 4; ++q) {
        int c = blockIdx.x * 32 + ty + q * 8;  // output row (= original col)
        int r = blockIdx.y * 32 + tx;          // output col (= original row)
        float v = t[tx][ty + q * 8];
        size_t idx = (size_t)c * R + r;
        f16 h = (f16)v;
        hi[idx] = h;
        lo[idx] = (f16)(v - (float)h);
    }
}

// ---------------------------------------------------------------------------
// Stage a 128x32 fp16 tile (row-major, ld = K) into LDS via global_load_lds.
// LDS layout: 512 slots of 16B; slot p = r*4 + c'' where the data is global
// chunk c = c'' ^ ((r>>1)&3)  (XOR swizzle applied on the GLOBAL source so the
// LDS destination stays linear — global_load_lds requirement).
// ---------------------------------------------------------------------------
__device__ __forceinline__ void stage128x32(const f16* __restrict__ src, int ld,
                                            f16* lds_tile, int w, int l) {
#pragma unroll
    for (int q = 0; q < 2; ++q) {
        int p = (w * 2 + q) * 64 + l;           // slot 0..511
        int r = p >> 2;                         // tile row 0..127
        int c = (p & 3) ^ ((r >> 1) & 3);       // swizzled global 16B chunk
        const f16* g = src + r * ld + c * 8;
        f16* d = lds_tile + (w * 2 + q) * 512;  // wave-uniform base
        __builtin_amdgcn_global_load_lds((const GAS void*)g, (LAS void*)d, 16, 0, 0);
    }
}

// ---------------------------------------------------------------------------
// Generic NT GEMM: C[M,N] = A[M,K] * B'[N,K]^T   (both operands fp16)
// SPLIT3: A,B given as hi/lo pairs; 3-pass MFMA for ~fp32 product accuracy.
// OUT_MODE: 0 = fp32 C, 1 = fp16 hi/lo split C, 2 = fp16 C.
// CAUSAL_SKIP: skip blocks strictly above the diagonal (gemm2).
// KCAP_CAUSAL: cap K at row0+128 (gemm3; A cols beyond are zero).
// 128x128 tile, BK=32, 256 threads = 4 waves in 2x2, each wave 64x64 out.
// T3 minimum-2-phase: double-buffered LDS; per K-step:
//   ds_read(cur) -> stage(next -> buf^1) -> MFMA -> __syncthreads -> flip.
// One vmcnt(0)+barrier per K-step; prefetch flies under ds_read+MFMA.
// ---------------------------------------------------------------------------
template <bool SPLIT3, int OUT_MODE, bool CAUSAL_SKIP, bool KCAP_CAUSAL>
__global__ __launch_bounds__(256) void gemm_nt(
    const f16* __restrict__ Ah, const f16* __restrict__ Al,
    const f16* __restrict__ Bh, const f16* __restrict__ Bl,
    float* __restrict__ Cf, f16* __restrict__ Ch, f16* __restrict__ Cl,
    int M, int N, int K) {
    const int row0 = blockIdx.y * 128;
    const int col0 = blockIdx.x * 128;
    if (CAUSAL_SKIP) {
        if (col0 > row0 + 127) return;  // wholly above diagonal: never read
    }
    int Keff = K;
    if (KCAP_CAUSAL) {
        Keff = row0 + 128;
        if (Keff > K) Keff = K;
    }

    constexpr int NT = SPLIT3 ? 4 : 2;        // operand tiles per buffer
    constexpr int TILE = 128 * 32;            // f16 elements per tile
    __shared__ f16 lds[2 * NT * TILE];        // double buffer

    const int tid = threadIdx.x;
    const int w = tid >> 6, l = tid & 63;
    const int wm = w >> 1, wn = w & 1;
    const int lr = l & 15;   // row within 16x16 fragment
    const int kg = l >> 4;   // k-group (8 consecutive k per group)
    const int cswz = kg ^ ((lr >> 1) & 3);
    const int aoff = (wm * 64 + lr) * 32 + cswz * 8;
    const int boff = (wn * 64 + lr) * 32 + cswz * 8;

    const f16* Asrc = Ah + (size_t)row0 * K;
    const f16* Bsrc = Bh + (size_t)col0 * K;
    const f16* Asrc_l = SPLIT3 ? Al + (size_t)row0 * K : nullptr;
    const f16* Bsrc_l = SPLIT3 ? Bl + (size_t)col0 * K : nullptr;

    auto stage_all = [&](int buf, int k0) {
        f16* base = lds + buf * NT * TILE;
        stage128x32(Asrc + k0, K, base + 0 * TILE, w, l);
        stage128x32(Bsrc + k0, K, base + 1 * TILE, w, l);
        if constexpr (SPLIT3) {
            stage128x32(Asrc_l + k0, K, base + 2 * TILE, w, l);
            stage128x32(Bsrc_l + k0, K, base + 3 * TILE, w, l);
        }
    };

    f32x4 acc[4][4] = {};

    // prologue: fill buffer 0
    stage_all(0, 0);
    __syncthreads();  // vmcnt(0) drain: tile 0 resident

    int cur = 0;
    for (int k0 = 0; k0 < Keff; k0 += 32) {
        const f16* base = lds + cur * NT * TILE;
        const f16* Ah_t = base;
        const f16* Bh_t = base + 1 * TILE;
        const f16* Al_t = base + 2 * TILE;
        const f16* Bl_t = base + 3 * TILE;

        // 1) issue ds_reads of current fragments (before any LDS-writing op)
        f16x8 ah[4], bh[4], al[4], bl[4];
#pragma unroll
        for (int m = 0; m < 4; ++m) {
            ah[m] = *(const f16x8*)&Ah_t[aoff + m * 512];
            if constexpr (SPLIT3) al[m] = *(const f16x8*)&Al_t[aoff + m * 512];
        }
#pragma unroll
        for (int n = 0; n < 4; ++n) {
            bh[n] = *(const f16x8*)&Bh_t[boff + n * 512];
            if constexpr (SPLIT3) bl[n] = *(const f16x8*)&Bl_t[boff + n * 512];
        }

        // 2) prefetch next K-tile into the other buffer (in flight under MFMA)
        const int kn = k0 + 32;
        if (kn < Keff) stage_all(cur ^ 1, kn);

        // 3) MFMA (compiler inserts lgkmcnt waits for the ds_read data)
#pragma unroll
        for (int m = 0; m < 4; ++m)
#pragma unroll
            for (int n = 0; n < 4; ++n) {
                acc[m][n] = __builtin_amdgcn_mfma_f32_16x16x32_f16(ah[m], bh[n],
                                                                   acc[m][n], 0, 0, 0);
                if constexpr (SPLIT3) {
                    acc[m][n] = __builtin_amdgcn_mfma_f32_16x16x32_f16(
                        al[m], bh[n], acc[m][n], 0, 0, 0);
                    acc[m][n] = __builtin_amdgcn_mfma_f32_16x16x32_f16(
                        ah[m], bl[n], acc[m][n], 0, 0, 0);
                }
            }

        // 4) one barrier per K-step: drains prefetch (vmcnt 0) + all waves'
        //    ds_reads of cur done -> next iter may read buf^1 / overwrite cur
        __syncthreads();
        cur ^= 1;
    }

    // Epilogue. C/D layout: col = lane&15, row = (lane>>4)*4 + reg  [m89/m91]
#pragma unroll
    for (int m = 0; m < 4; ++m)
#pragma unroll
        for (int n = 0; n < 4; ++n)
#pragma unroll
            for (int j = 0; j < 4; ++j) {
                int row = row0 + wm * 64 + m * 16 + kg * 4 + j;
                int col = col0 + wn * 64 + n * 16 + lr;
                size_t idx = (size_t)row * N + col;
                float v = acc[m][n][j];
                if constexpr (OUT_MODE == 0) {
                    Cf[idx] = v;
                } else if constexpr (OUT_MODE == 1) {
                    f16 h = (f16)v;
                    Ch[idx] = h;
                    Cl[idx] = (f16)(v - (float)h);
                } else {
                    Ch[idx] = (f16)v;
                }
            }
}

// ---------------------------------------------------------------------------
// Causal row softmax: logits [T,T] fp32 -> attn [T,T] fp16.
// Row i uses cols 0..i; writes zeros for i < j < jmax (next 128 boundary,
// which is all gemm3 will ever read).
// ---------------------------------------------------------------------------
__global__ void softmax_causal(const float* __restrict__ L, f16* __restrict__ A) {
    const int i = blockIdx.x;
    const int n = i + 1;
    const int tid = threadIdx.x;  // 256 threads
    const float* row = L + (size_t)i * T_DIM;
    f16* arow = A + (size_t)i * T_DIM;

    float m = -INFINITY, s = 0.f;
    for (int j = tid; j < n; j += 256) {
        float v = row[j];
        if (v > m) {
            s = s * __expf(m - v) + 1.f;
            m = v;
        } else {
            s += __expf(v - m);
        }
    }

    __shared__ float sm[256], ss[256];
    sm[tid] = m;
    ss[tid] = s;
    __syncthreads();
    for (int o = 128; o > 0; o >>= 1) {
        if (tid < o) {
            float m1 = sm[tid], s1 = ss[tid];
            float m2 = sm[tid + o], s2 = ss[tid + o];
            float M = fmaxf(m1, m2);
            float S = (M == -INFINITY) ? 0.f
                                       : s1 * __expf(m1 - M) + s2 * __expf(m2 - M);
            sm[tid] = M;
            ss[tid] = S;
        }
        __syncthreads();
    }
    const float M = sm[0];
    const float inv = 1.f / ss[0];

    const int jmax = ((i >> 7) + 1) << 7;  // gemm3 reads cols < this
    for (int j = tid; j < jmax; j += 256) {
        float v = (j < n) ? __expf(row[j] - M) * inv : 0.f;
        arow[j] = (f16)v;
    }
}

// ---------------------------------------------------------------------------
extern "C" void kernel_launch(void* const* d_in, const int* in_sizes, int n_in,
                              void* d_out, int out_size, void* d_ws, size_t ws_size,
                              hipStream_t stream) {
    (void)in_sizes; (void)n_in; (void)out_size; (void)ws_size;
    const float* x = (const float*)d_in[0];
    const float* wqk = (const float*)d_in[1];
    const float* wov = (const float*)d_in[2];
    float* out = (float*)d_out;
    char* ws = (char*)d_ws;
    const size_t MB = 1024 * 1024;

    f16* x_hi    = (f16*)(ws + 0 * MB);    // 8 MB  [T][D]
    f16* x_lo    = (f16*)(ws + 8 * MB);    // 8 MB
    f16* wqkT_hi = (f16*)(ws + 16 * MB);   // 2 MB  [D][D] (= Wqk^T)
    f16* wqkT_lo = (f16*)(ws + 18 * MB);   // 2 MB
    f16* wovT_hi = (f16*)(ws + 20 * MB);   // 2 MB
    f16* wovT_lo = (f16*)(ws + 22 * MB);   // 2 MB
    f16* xT_hi   = (f16*)(ws + 24 * MB);   // 8 MB  [D][T]
    f16* xT_lo   = (f16*)(ws + 32 * MB);   // 8 MB (unused downstream)
    f16* q_hi    = (f16*)(ws + 40 * MB);   // 8 MB  [T][D]
    f16* q_lo    = (f16*)(ws + 48 * MB);   // 8 MB
    f16* z_hi    = (f16*)(ws + 56 * MB);   // 8 MB  [T][D]
    f16* attn    = (f16*)(ws + 64 * MB);   // 32 MB [T][T]
    float* logit = (float*)(ws + 96 * MB); // 64 MB [T][T]
    // total: 160 MB

    // 1) splits / transposes
    split4<<<(T_DIM * D_DIM) / 1024, 256, 0, stream>>>(x, x_hi, x_lo);
    transpose_split<<<dim3(D_DIM / 32, D_DIM / 32), 256, 0, stream>>>(
        wqk, wqkT_hi, wqkT_lo, D_DIM, D_DIM);
    transpose_split<<<dim3(D_DIM / 32, D_DIM / 32), 256, 0, stream>>>(
        wov, wovT_hi, wovT_lo, D_DIM, D_DIM);
    transpose_split<<<dim3(D_DIM / 32, T_DIM / 32), 256, 0, stream>>>(
        x, xT_hi, xT_lo, T_DIM, D_DIM);

    // 2) Q = x @ Wqk  (3-pass split in, fp16 hi/lo out)
    gemm_nt<true, 1, false, false>
        <<<dim3(D_DIM / 128, T_DIM / 128), 256, 0, stream>>>(
            x_hi, x_lo, wqkT_hi, wqkT_lo, nullptr, q_hi, q_lo, T_DIM, D_DIM, D_DIM);

    // 3) logits = Q @ x^T  (3-pass split, fp32 out, causal block skip)
    gemm_nt<true, 0, true, false>
        <<<dim3(T_DIM / 128, T_DIM / 128), 256, 0, stream>>>(
            q_hi, q_lo, x_hi, x_lo, logit, nullptr, nullptr, T_DIM, T_DIM, D_DIM);

    // 4) attn = causal softmax(logits)
    softmax_causal<<<T_DIM, 256, 0, stream>>>(logit, attn);

    // 5) z = attn @ x  (single-pass fp16, K capped at diagonal)
    gemm_nt<false, 2, false, true>
        <<<dim3(D_DIM / 128, T_DIM / 128), 256, 0, stream>>>(
            attn, nullptr, xT_hi, nullptr, nullptr, z_hi, nullptr, T_DIM, D_DIM, T_DIM);

    // 6) out = z @ Wov  (single-pass fp16, fp32 out)
    gemm_nt<false, 0, false, false>
        <<<dim3(D_DIM / 128, T_DIM / 128), 256, 0, stream>>>(
            z_hi, nullptr, wovT_hi, nullptr, out, nullptr, nullptr, T_DIM, D_DIM, D_DIM);
}

// Round 9
// 291.930 us; speedup vs baseline: 1.2249x; 1.0812x over previous
//
#include <hip/hip_runtime.h>
#include <hip/hip_fp16.h>

#define T_DIM 4096
#define D_DIM 1024

typedef _Float16 f16;
typedef _Float16 f16x4 __attribute__((ext_vector_type(4)));
typedef _Float16 f16x8 __attribute__((ext_vector_type(8)));
typedef float f32x4 __attribute__((ext_vector_type(4)));

#define GAS __attribute__((address_space(1)))
#define LAS __attribute__((address_space(3)))

// ---------------------------------------------------------------------------
// Preprocessing: fp32 -> fp16 hi/lo split (flat, vectorized x4)
// ---------------------------------------------------------------------------
__global__ void split4(const float* __restrict__ in, f16* __restrict__ hi,
                       f16* __restrict__ lo) {
    int i = (blockIdx.x * 256 + threadIdx.x) * 4;
    float4 v = *(const float4*)(in + i);
    float vv[4] = {v.x, v.y, v.z, v.w};
    f16x4 h, l;
#pragma unroll
    for (int j = 0; j < 4; ++j) {
        f16 hh = (f16)vv[j];
        h[j] = hh;
        l[j] = (f16)(vv[j] - (float)hh);
    }
    *(f16x4*)(hi + i) = h;
    *(f16x4*)(lo + i) = l;
}

// ---------------------------------------------------------------------------
// Preprocessing: transpose + split.  in [R][C] fp32 -> hi/lo [C][R] fp16
// ---------------------------------------------------------------------------
__global__ void transpose_split(const float* __restrict__ in, f16* __restrict__ hi,
                                f16* __restrict__ lo, int R, int C) {
    __shared__ float t[32][33];
    int tx = threadIdx.x & 31;
    int ty = threadIdx.x >> 5;  // 0..7
#pragma unroll
    for (int q = 0; q < 4; ++q) {
        int r = blockIdx.y * 32 + ty + q * 8;
        int c = blockIdx.x * 32 + tx;
        t[ty + q * 8][tx] = in[(size_t)r * C + c];
    }
    __syncthreads();
#pragma unroll
    for (int q = 0; q < 4; ++q) {
        int c = blockIdx.x * 32 + ty + q * 8;  // output row (= original col)
        int r = blockIdx.y * 32 + tx;          // output col (= original row)
        float v = t[tx][ty + q * 8];
        size_t idx = (size_t)c * R + r;
        f16 h = (f16)v;
        hi[idx] = h;
        lo[idx] = (f16)(v - (float)h);
    }
}

// ---------------------------------------------------------------------------
// Stage a ROWSx32 fp16 tile (row-major, ld = K) into LDS via global_load_lds.
// LDS layout: ROWS*4 slots of 16B; slot p = r*4 + c'' where the data is global
// chunk c = c'' ^ ((r>>1)&3)  (XOR swizzle applied on the GLOBAL source so the
// LDS destination stays linear — global_load_lds requirement).
// 256 threads; ROWS*4/256 loads per thread; LDS dest is wave-uniform base.
// ---------------------------------------------------------------------------
template <int ROWS>
__device__ __forceinline__ void stage_tile(const f16* __restrict__ src, int ld,
                                           f16* lds_tile, int w, int l) {
    constexpr int ITER = (ROWS * 4) / 256;
#pragma unroll
    for (int q = 0; q < ITER; ++q) {
        int p = q * 256 + w * 64 + l;           // slot id
        int r = p >> 2;                         // tile row
        int c = (p & 3) ^ ((r >> 1) & 3);       // swizzled global 16B chunk
        const f16* g = src + r * ld + c * 8;
        f16* d = lds_tile + (q * 256 + w * 64) * 8;  // wave-uniform base
        __builtin_amdgcn_global_load_lds((const GAS void*)g, (LAS void*)d, 16, 0, 0);
    }
}

// ---------------------------------------------------------------------------
// Generic NT GEMM: C[M,N] = A[M,K] * B'[N,K]^T   (both operands fp16)
// TM x TN block tile, BK=32, 256 threads = 4 waves in 2x2; wave tile
// (TM/2)x(TN/2); M_REP=TM/32, N_REP=TN/32 fragments of 16x16.
// SPLIT3: A,B given as hi/lo pairs; 3-pass MFMA for ~fp32 product accuracy.
// OUT_MODE: 0 = fp32 C, 1 = fp16 hi/lo split C, 2 = fp16 C.
// CAUSAL_SKIP: skip blocks strictly above the diagonal (gemm2).
// KCAP_CAUSAL: cap K at row0+TM (gemm3; A cols beyond are zero).
// REVY: reverse blockIdx.y so longest-K blocks dispatch first (KCAP balance).
// 2-phase dbuf; per K-step: stage(next->buf^1) FIRST (max latency cover),
// then ds_read(cur) -> MFMA -> one barrier -> flip.
// ---------------------------------------------------------------------------
template <int TM, int TN, bool SPLIT3, int OUT_MODE, bool CAUSAL_SKIP,
          bool KCAP_CAUSAL, bool REVY>
__global__ __launch_bounds__(256) void gemm_nt(
    const f16* __restrict__ Ah, const f16* __restrict__ Al,
    const f16* __restrict__ Bh, const f16* __restrict__ Bl,
    float* __restrict__ Cf, f16* __restrict__ Ch, f16* __restrict__ Cl,
    int M, int N, int K) {
    const int by = REVY ? (gridDim.y - 1 - blockIdx.y) : blockIdx.y;
    const int row0 = by * TM;
    const int col0 = blockIdx.x * TN;
    if (CAUSAL_SKIP) {
        if (col0 > row0 + TM - 1) return;  // wholly above diagonal: never read
    }
    int Keff = K;
    if (KCAP_CAUSAL) {
        Keff = row0 + TM;
        if (Keff > K) Keff = K;
    }

    constexpr int TILE_A = TM * 32;           // f16 elems per A tile
    constexpr int TILE_B = TN * 32;
    constexpr int BUFSZ = (SPLIT3 ? 2 : 1) * (TILE_A + TILE_B);
    constexpr int M_REP = TM / 32;
    constexpr int N_REP = TN / 32;
    __shared__ f16 lds[2 * BUFSZ];            // double buffer

    const int tid = threadIdx.x;
    const int w = tid >> 6, l = tid & 63;
    const int wm = w >> 1, wn = w & 1;
    const int lr = l & 15;   // row within 16x16 fragment
    const int kg = l >> 4;   // k-group (8 consecutive k per group)
    const int cswz = kg ^ ((lr >> 1) & 3);
    // (row>>1)&3 == (lr>>1)&3 for all frag rows: wave/frag offsets are =0 mod 32
    const int aoff = (wm * (TM / 2) + lr) * 32 + cswz * 8;
    const int boff = (wn * (TN / 2) + lr) * 32 + cswz * 8;

    const f16* Asrc = Ah + (size_t)row0 * K;
    const f16* Bsrc = Bh + (size_t)col0 * K;
    const f16* Asrc_l = SPLIT3 ? Al + (size_t)row0 * K : nullptr;
    const f16* Bsrc_l = SPLIT3 ? Bl + (size_t)col0 * K : nullptr;

    auto stage_all = [&](int buf, int k0) {
        f16* base = lds + buf * BUFSZ;
        stage_tile<TM>(Asrc + k0, K, base, w, l);
        stage_tile<TN>(Bsrc + k0, K, base + TILE_A, w, l);
        if constexpr (SPLIT3) {
            stage_tile<TM>(Asrc_l + k0, K, base + TILE_A + TILE_B, w, l);
            stage_tile<TN>(Bsrc_l + k0, K, base + 2 * TILE_A + TILE_B, w, l);
        }
    };

    f32x4 acc[M_REP][N_REP] = {};

    // prologue: fill buffer 0
    stage_all(0, 0);
    __syncthreads();  // vmcnt(0) drain: tile 0 resident

    int cur = 0;
    for (int k0 = 0; k0 < Keff; k0 += 32) {
        // 1) prefetch next K-tile into the other buffer FIRST — maximum
        //    latency cover before the barrier's vmcnt(0) drain.
        const int kn = k0 + 32;
        if (kn < Keff) stage_all(cur ^ 1, kn);

        const f16* base = lds + cur * BUFSZ;
        const f16* Ah_t = base;
        const f16* Bh_t = base + TILE_A;
        const f16* Al_t = base + TILE_A + TILE_B;
        const f16* Bl_t = base + 2 * TILE_A + TILE_B;

        // 2) ds_read current fragments (disjoint from the staging buffer)
        f16x8 ah[M_REP], bh[N_REP], al[M_REP], bl[N_REP];
#pragma unroll
        for (int m = 0; m < M_REP; ++m) {
            ah[m] = *(const f16x8*)&Ah_t[aoff + m * 512];
            if constexpr (SPLIT3) al[m] = *(const f16x8*)&Al_t[aoff + m * 512];
        }
#pragma unroll
        for (int n = 0; n < N_REP; ++n) {
            bh[n] = *(const f16x8*)&Bh_t[boff + n * 512];
            if constexpr (SPLIT3) bl[n] = *(const f16x8*)&Bl_t[boff + n * 512];
        }

        // 3) MFMA (compiler inserts lgkmcnt waits for the ds_read data)
#pragma unroll
        for (int m = 0; m < M_REP; ++m)
#pragma unroll
            for (int n = 0; n < N_REP; ++n) {
                acc[m][n] = __builtin_amdgcn_mfma_f32_16x16x32_f16(ah[m], bh[n],
                                                                   acc[m][n], 0, 0, 0);
                if constexpr (SPLIT3) {
                    acc[m][n] = __builtin_amdgcn_mfma_f32_16x16x32_f16(
                        al[m], bh[n], acc[m][n], 0, 0, 0);
                    acc[m][n] = __builtin_amdgcn_mfma_f32_16x16x32_f16(
                        ah[m], bl[n], acc[m][n], 0, 0, 0);
                }
            }

        // 4) one barrier per K-step: drains prefetch (vmcnt 0) + all waves'
        //    ds_reads of cur done -> next iter may read buf^1 / overwrite cur
        __syncthreads();
        cur ^= 1;
    }

    // Epilogue. C/D layout: col = lane&15, row = (lane>>4)*4 + reg  [m89/m91]
#pragma unroll
    for (int m = 0; m < M_REP; ++m)
#pragma unroll
        for (int n = 0; n < N_REP; ++n)
#pragma unroll
            for (int j = 0; j < 4; ++j) {
                int row = row0 + wm * (TM / 2) + m * 16 + kg * 4 + j;
                int col = col0 + wn * (TN / 2) + n * 16 + lr;
                size_t idx = (size_t)row * N + col;
                float v = acc[m][n][j];
                if constexpr (OUT_MODE == 0) {
                    Cf[idx] = v;
                } else if constexpr (OUT_MODE == 1) {
                    f16 h = (f16)v;
                    Ch[idx] = h;
                    Cl[idx] = (f16)(v - (float)h);
                } else {
                    Ch[idx] = (f16)v;
                }
            }
}

// ---------------------------------------------------------------------------
// Causal row softmax: logits [T,T] fp32 -> attn [T,T] fp16.
// Row i uses cols 0..i; writes zeros for i < j < jmax (next 128 boundary,
// which is all gemm3 will ever read).
// ---------------------------------------------------------------------------
__global__ void softmax_causal(const float* __restrict__ L, f16* __restrict__ A) {
    const int i = blockIdx.x;
    const int n = i + 1;
    const int tid = threadIdx.x;  // 256 threads
    const float* row = L + (size_t)i * T_DIM;
    f16* arow = A + (size_t)i * T_DIM;

    float m = -INFINITY, s = 0.f;
    for (int j = tid; j < n; j += 256) {
        float v = row[j];
        if (v > m) {
            s = s * __expf(m - v) + 1.f;
            m = v;
        } else {
            s += __expf(v - m);
        }
    }

    __shared__ float sm[256], ss[256];
    sm[tid] = m;
    ss[tid] = s;
    __syncthreads();
    for (int o = 128; o > 0; o >>= 1) {
        if (tid < o) {
            float m1 = sm[tid], s1 = ss[tid];
            float m2 = sm[tid + o], s2 = ss[tid + o];
            float M = fmaxf(m1, m2);
            float S = (M == -INFINITY) ? 0.f
                                       : s1 * __expf(m1 - M) + s2 * __expf(m2 - M);
            sm[tid] = M;
            ss[tid] = S;
        }
        __syncthreads();
    }
    const float M = sm[0];
    const float inv = 1.f / ss[0];

    const int jmax = ((i >> 7) + 1) << 7;  // gemm3 reads cols < this
    for (int j = tid; j < jmax; j += 256) {
        float v = (j < n) ? __expf(row[j] - M) * inv : 0.f;
        arow[j] = (f16)v;
    }
}

// ---------------------------------------------------------------------------
extern "C" void kernel_launch(void* const* d_in, const int* in_sizes, int n_in,
                              void* d_out, int out_size, void* d_ws, size_t ws_size,
                              hipStream_t stream) {
    (void)in_sizes; (void)n_in; (void)out_size; (void)ws_size;
    const float* x = (const float*)d_in[0];
    const float* wqk = (const float*)d_in[1];
    const float* wov = (const float*)d_in[2];
    float* out = (float*)d_out;
    char* ws = (char*)d_ws;
    const size_t MB = 1024 * 1024;

    f16* x_hi    = (f16*)(ws + 0 * MB);    // 8 MB  [T][D]
    f16* x_lo    = (f16*)(ws + 8 * MB);    // 8 MB
    f16* wqkT_hi = (f16*)(ws + 16 * MB);   // 2 MB  [D][D] (= Wqk^T)
    f16* wqkT_lo = (f16*)(ws + 18 * MB);   // 2 MB
    f16* wovT_hi = (f16*)(ws + 20 * MB);   // 2 MB
    f16* wovT_lo = (f16*)(ws + 22 * MB);   // 2 MB
    f16* xT_hi   = (f16*)(ws + 24 * MB);   // 8 MB  [D][T]
    f16* xT_lo   = (f16*)(ws + 32 * MB);   // 8 MB (unused downstream)
    f16* q_hi    = (f16*)(ws + 40 * MB);   // 8 MB  [T][D]
    f16* q_lo    = (f16*)(ws + 48 * MB);   // 8 MB
    f16* z_hi    = (f16*)(ws + 56 * MB);   // 8 MB  [T][D]
    f16* attn    = (f16*)(ws + 64 * MB);   // 32 MB [T][T]
    float* logit = (float*)(ws + 96 * MB); // 64 MB [T][T]
    // total: 160 MB

    // 1) splits / transposes
    split4<<<(T_DIM * D_DIM) / 1024, 256, 0, stream>>>(x, x_hi, x_lo);
    transpose_split<<<dim3(D_DIM / 32, D_DIM / 32), 256, 0, stream>>>(
        wqk, wqkT_hi, wqkT_lo, D_DIM, D_DIM);
    transpose_split<<<dim3(D_DIM / 32, D_DIM / 32), 256, 0, stream>>>(
        wov, wovT_hi, wovT_lo, D_DIM, D_DIM);
    transpose_split<<<dim3(D_DIM / 32, T_DIM / 32), 256, 0, stream>>>(
        x, xT_hi, xT_lo, T_DIM, D_DIM);

    // 2) Q = x @ Wqk  (3-pass split in, fp16 hi/lo out)
    //    128x64 tile -> 512 blocks, ~3 blocks/CU (48 KB LDS): TLP hides latency
    gemm_nt<128, 64, true, 1, false, false, false>
        <<<dim3(D_DIM / 64, T_DIM / 128), 256, 0, stream>>>(
            x_hi, x_lo, wqkT_hi, wqkT_lo, nullptr, q_hi, q_lo, T_DIM, D_DIM, D_DIM);

    // 3) logits = Q @ x^T  (3-pass split, fp32 out, causal block skip)
    //    128x128 kept: isolates the stage-first reorder vs round-6
    gemm_nt<128, 128, true, 0, true, false, false>
        <<<dim3(T_DIM / 128, T_DIM / 128), 256, 0, stream>>>(
            q_hi, q_lo, x_hi, x_lo, logit, nullptr, nullptr, T_DIM, T_DIM, D_DIM);

    // 4) attn = causal softmax(logits)
    softmax_causal<<<T_DIM, 256, 0, stream>>>(logit, attn);

    // 5) z = attn @ x  (single-pass fp16, K capped at diagonal)
    //    128x64 tile -> 512 blocks, 2+/CU; REVY: longest-K rows dispatch first
    gemm_nt<128, 64, false, 2, false, true, true>
        <<<dim3(D_DIM / 64, T_DIM / 128), 256, 0, stream>>>(
            attn, nullptr, xT_hi, nullptr, nullptr, z_hi, nullptr, T_DIM, D_DIM, T_DIM);

    // 6) out = z @ Wov  (single-pass fp16, fp32 out), 128x64 tile
    gemm_nt<128, 64, false, 0, false, false, false>
        <<<dim3(D_DIM / 64, T_DIM / 128), 256, 0, stream>>>(
            z_hi, nullptr, wovT_hi, nullptr, out, nullptr, nullptr, T_DIM, D_DIM, D_DIM);
}

// Round 11
// 283.767 us; speedup vs baseline: 1.2602x; 1.0288x over previous
//
#include <hip/hip_runtime.h>
#include <hip/hip_fp16.h>

#define T_DIM 4096
#define D_DIM 1024

typedef _Float16 f16;
typedef _Float16 f16x4 __attribute__((ext_vector_type(4)));
typedef _Float16 f16x8 __attribute__((ext_vector_type(8)));
typedef float f32x4 __attribute__((ext_vector_type(4)));

#define GAS __attribute__((address_space(1)))
#define LAS __attribute__((address_space(3)))

// ---------------------------------------------------------------------------
// Preprocessing: fp32 -> fp16 hi/lo split (flat, vectorized x4)
// ---------------------------------------------------------------------------
__global__ void split4(const float* __restrict__ in, f16* __restrict__ hi,
                       f16* __restrict__ lo) {
    int i = (blockIdx.x * 256 + threadIdx.x) * 4;
    float4 v = *(const float4*)(in + i);
    float vv[4] = {v.x, v.y, v.z, v.w};
    f16x4 h, l;
#pragma unroll
    for (int j = 0; j < 4; ++j) {
        f16 hh = (f16)vv[j];
        h[j] = hh;
        l[j] = (f16)(vv[j] - (float)hh);
    }
    *(f16x4*)(hi + i) = h;
    *(f16x4*)(lo + i) = l;
}

// ---------------------------------------------------------------------------
// Preprocessing: transpose + split.  in [R][C] fp32 -> hi/lo [C][R] fp16
// ---------------------------------------------------------------------------
__global__ void transpose_split(const float* __restrict__ in, f16* __restrict__ hi,
                                f16* __restrict__ lo, int R, int C) {
    __shared__ float t[32][33];
    int tx = threadIdx.x & 31;
    int ty = threadIdx.x >> 5;  // 0..7
#pragma unroll
    for (int q = 0; q < 4; ++q) {
        int r = blockIdx.y * 32 + ty + q * 8;
        int c = blockIdx.x * 32 + tx;
        t[ty + q * 8][tx] = in[(size_t)r * C + c];
    }
    __syncthreads();
#pragma unroll
    for (int q = 0; q < 4; ++q) {
        int c = blockIdx.x * 32 + ty + q * 8;  // output row (= original col)
        int r = blockIdx.y * 32 + tx;          // output col (= original row)
        float v = t[tx][ty + q * 8];
        size_t idx = (size_t)c * R + r;
        f16 h = (f16)v;
        hi[idx] = h;
        lo[idx] = (f16)(v - (float)h);
    }
}

// ---------------------------------------------------------------------------
// Stage a ROWSx32 fp16 tile (row-major, ld = K) into LDS via global_load_lds.
// LDS layout: ROWS*4 slots of 16B; slot p = r*4 + c'' where the data is global
// chunk c = c'' ^ ((r>>1)&3)  (XOR swizzle applied on the GLOBAL source so the
// LDS destination stays linear — global_load_lds requirement).
// 256 threads; ROWS*4/256 loads per thread; LDS dest is wave-uniform base.
// ---------------------------------------------------------------------------
template <int ROWS>
__device__ __forceinline__ void stage_tile(const f16* __restrict__ src, int ld,
                                           f16* lds_tile, int w, int l) {
    constexpr int ITER = (ROWS * 4) / 256;
#pragma unroll
    for (int q = 0; q < ITER; ++q) {
        int p = q * 256 + w * 64 + l;           // slot id
        int r = p >> 2;                         // tile row
        int c = (p & 3) ^ ((r >> 1) & 3);       // swizzled global 16B chunk
        const f16* g = src + r * ld + c * 8;
        f16* d = lds_tile + (q * 256 + w * 64) * 8;  // wave-uniform base
        __builtin_amdgcn_global_load_lds((const GAS void*)g, (LAS void*)d, 16, 0, 0);
    }
}

// Counted vmcnt wait — immediate must be a literal, so if-constexpr dispatch.
template <int N>
__device__ __forceinline__ void vm_wait() {
    static_assert(N == 0 || N == 3 || N == 6 || N == 8, "unsupported vmcnt");
    if constexpr (N == 0) asm volatile("s_waitcnt vmcnt(0)" ::: "memory");
    else if constexpr (N == 3) asm volatile("s_waitcnt vmcnt(3)" ::: "memory");
    else if constexpr (N == 6) asm volatile("s_waitcnt vmcnt(6)" ::: "memory");
    else if constexpr (N == 8) asm volatile("s_waitcnt vmcnt(8)" ::: "memory");
}

// ---------------------------------------------------------------------------
// Generic NT GEMM: C[M,N] = A[M,K] * B'[N,K]^T   (both operands fp16)
// TM x TN block tile, BK=32, 256 threads = 4 waves in 2x2; wave tile
// (TM/2)x(TN/2); M_REP=TM/32, N_REP=TN/32 fragments of 16x16.
// SPLIT3: A,B given as hi/lo pairs; 3-pass MFMA for ~fp32 product accuracy.
// OUT_MODE: 0 = fp32 C, 1 = fp16 hi/lo split C, 2 = fp16 C.
// CAUSAL_SKIP: skip blocks strictly above the diagonal (gemm2).
// KCAP_CAUSAL: cap K at row0+TM (gemm3; A cols beyond are zero).
// REVY: reverse blockIdx.y so longest-K blocks dispatch first (KCAP balance).
//
// T4 depth-2 counted-vmcnt pipeline (no vmcnt(0) drain in steady state):
//   prologue: stage tile0 -> buf0, tile1 -> buf1        (2*LPS loads in flight)
//   step i:   vmcnt(LPS)           // tile i resident; tile i+1 still flying
//             s_barrier            // B1: all waves agree
//             ds_read frags(buf[i&1])
//             lgkmcnt(0); s_barrier // B2: all waves' reads done -> buf free
//             stage tile i+2 -> buf[i&1]   (i+2 < nsteps)
//             MFMA                 // covers the new stage's flight
//   last step waits vmcnt(0) (peeled via conditional).
// Loads get ~2 K-steps of flight before being waited on (covers ~900cy HBM).
// Barrier counts are block-uniform: stage/wait conditions depend only on i.
// ---------------------------------------------------------------------------
template <int TM, int TN, bool SPLIT3, int OUT_MODE, bool CAUSAL_SKIP,
          bool KCAP_CAUSAL, bool REVY>
__global__ __launch_bounds__(256) void gemm_nt(
    const f16* __restrict__ Ah, const f16* __restrict__ Al,
    const f16* __restrict__ Bh, const f16* __restrict__ Bl,
    float* __restrict__ Cf, f16* __restrict__ Ch, f16* __restrict__ Cl,
    int M, int N, int K) {
    const int by = REVY ? (gridDim.y - 1 - blockIdx.y) : blockIdx.y;
    const int row0 = by * TM;
    const int col0 = blockIdx.x * TN;
    if (CAUSAL_SKIP) {
        if (col0 > row0 + TM - 1) return;  // wholly above diagonal: never read
    }
    int Keff = K;
    if (KCAP_CAUSAL) {
        Keff = row0 + TM;
        if (Keff > K) Keff = K;
    }

    constexpr int TILE_A = TM * 32;           // f16 elems per A tile
    constexpr int TILE_B = TN * 32;
    constexpr int BUFSZ = (SPLIT3 ? 2 : 1) * (TILE_A + TILE_B);
    constexpr int M_REP = TM / 32;
    constexpr int N_REP = TN / 32;
    // loads per stage_all per thread (16B each): vmcnt bookkeeping constant
    constexpr int LPS = (SPLIT3 ? 2 : 1) * (TM + TN) / 64;
    __shared__ f16 lds[2 * BUFSZ];            // double buffer

    const int tid = threadIdx.x;
    const int w = tid >> 6, l = tid & 63;
    const int wm = w >> 1, wn = w & 1;
    const int lr = l & 15;   // row within 16x16 fragment
    const int kg = l >> 4;   // k-group (8 consecutive k per group)
    const int cswz = kg ^ ((lr >> 1) & 3);
    // (row>>1)&3 == (lr>>1)&3 for all frag rows: wave/frag offsets are =0 mod 32
    const int aoff = (wm * (TM / 2) + lr) * 32 + cswz * 8;
    const int boff = (wn * (TN / 2) + lr) * 32 + cswz * 8;

    const f16* Asrc = Ah + (size_t)row0 * K;
    const f16* Bsrc = Bh + (size_t)col0 * K;
    const f16* Asrc_l = SPLIT3 ? Al + (size_t)row0 * K : nullptr;
    const f16* Bsrc_l = SPLIT3 ? Bl + (size_t)col0 * K : nullptr;

    auto stage_all = [&](int buf, int k0) {
        f16* base = lds + buf * BUFSZ;
        stage_tile<TM>(Asrc + k0, K, base, w, l);
        stage_tile<TN>(Bsrc + k0, K, base + TILE_A, w, l);
        if constexpr (SPLIT3) {
            stage_tile<TM>(Asrc_l + k0, K, base + TILE_A + TILE_B, w, l);
            stage_tile<TN>(Bsrc_l + k0, K, base + 2 * TILE_A + TILE_B, w, l);
        }
    };

    f32x4 acc[M_REP][N_REP] = {};

    const int nsteps = Keff >> 5;  // >= 4 for all instantiations

    // prologue: fill both buffers (2*LPS loads in flight, no wait)
    stage_all(0, 0);
    stage_all(1, 32);

    int cur = 0;
    for (int i = 0; i < nsteps; ++i) {
        // B1: tile i resident (tile i+1's LPS loads may remain in flight)
        if (i + 1 < nsteps) vm_wait<LPS>(); else vm_wait<0>();
        __builtin_amdgcn_sched_barrier(0);
        __builtin_amdgcn_s_barrier();
        __builtin_amdgcn_sched_barrier(0);

        const f16* base = lds + cur * BUFSZ;
        const f16* Ah_t = base;
        const f16* Bh_t = base + TILE_A;
        const f16* Al_t = base + TILE_A + TILE_B;
        const f16* Bl_t = base + 2 * TILE_A + TILE_B;

        f16x8 ah[M_REP], bh[N_REP], al[M_REP], bl[N_REP];
#pragma unroll
        for (int m = 0; m < M_REP; ++m) {
            ah[m] = *(const f16x8*)&Ah_t[aoff + m * 512];
            if constexpr (SPLIT3) al[m] = *(const f16x8*)&Al_t[aoff + m * 512];
        }
#pragma unroll
        for (int n = 0; n < N_REP; ++n) {
            bh[n] = *(const f16x8*)&Bh_t[boff + n * 512];
            if constexpr (SPLIT3) bl[n] = *(const f16x8*)&Bl_t[boff + n * 512];
        }

        // B2: own ds_reads done ("memory" asm orders all LDS reads above it),
        // then barrier -> every wave's reads of buf[cur] complete -> buf free.
        asm volatile("s_waitcnt lgkmcnt(0)" ::: "memory");
        __builtin_amdgcn_sched_barrier(0);
        __builtin_amdgcn_s_barrier();
        __builtin_amdgcn_sched_barrier(0);

        // stage tile i+2 into the freed buffer; its flight is covered by this
        // step's MFMA + next step's pre-MFMA phase (~2 K-steps).
        if (i + 2 < nsteps) stage_all(cur, (i + 2) * 32);

#pragma unroll
        for (int m = 0; m < M_REP; ++m)
#pragma unroll
            for (int n = 0; n < N_REP; ++n) {
                acc[m][n] = __builtin_amdgcn_mfma_f32_16x16x32_f16(ah[m], bh[n],
                                                                   acc[m][n], 0, 0, 0);
                if constexpr (SPLIT3) {
                    acc[m][n] = __builtin_amdgcn_mfma_f32_16x16x32_f16(
                        al[m], bh[n], acc[m][n], 0, 0, 0);
                    acc[m][n] = __builtin_amdgcn_mfma_f32_16x16x32_f16(
                        ah[m], bl[n], acc[m][n], 0, 0, 0);
                }
            }

        cur ^= 1;
    }

    // Epilogue. C/D layout: col = lane&15, row = (lane>>4)*4 + reg  [m89/m91]
#pragma unroll
    for (int m = 0; m < M_REP; ++m)
#pragma unroll
        for (int n = 0; n < N_REP; ++n)
#pragma unroll
            for (int j = 0; j < 4; ++j) {
                int row = row0 + wm * (TM / 2) + m * 16 + kg * 4 + j;
                int col = col0 + wn * (TN / 2) + n * 16 + lr;
                size_t idx = (size_t)row * N + col;
                float v = acc[m][n][j];
                if constexpr (OUT_MODE == 0) {
                    Cf[idx] = v;
                } else if constexpr (OUT_MODE == 1) {
                    f16 h = (f16)v;
                    Ch[idx] = h;
                    Cl[idx] = (f16)(v - (float)h);
                } else {
                    Ch[idx] = (f16)v;
                }
            }
}

// ---------------------------------------------------------------------------
// Causal row softmax: logits [T,T] fp32 -> attn [T,T] fp16.
// Row i uses cols 0..i; writes zeros for i < j < jmax (next 128 boundary,
// which is all gemm3 will ever read).
// ---------------------------------------------------------------------------
__global__ void softmax_causal(const float* __restrict__ L, f16* __restrict__ A) {
    const int i = blockIdx.x;
    const int n = i + 1;
    const int tid = threadIdx.x;  // 256 threads
    const float* row = L + (size_t)i * T_DIM;
    f16* arow = A + (size_t)i * T_DIM;

    float m = -INFINITY, s = 0.f;
    for (int j = tid; j < n; j += 256) {
        float v = row[j];
        if (v > m) {
            s = s * __expf(m - v) + 1.f;
            m = v;
        } else {
            s += __expf(v - m);
        }
    }

    __shared__ float sm[256], ss[256];
    sm[tid] = m;
    ss[tid] = s;
    __syncthreads();
    for (int o = 128; o > 0; o >>= 1) {
        if (tid < o) {
            float m1 = sm[tid], s1 = ss[tid];
            float m2 = sm[tid + o], s2 = ss[tid + o];
            float M = fmaxf(m1, m2);
            float S = (M == -INFINITY) ? 0.f
                                       : s1 * __expf(m1 - M) + s2 * __expf(m2 - M);
            sm[tid] = M;
            ss[tid] = S;
        }
        __syncthreads();
    }
    const float M = sm[0];
    const float inv = 1.f / ss[0];

    const int jmax = ((i >> 7) + 1) << 7;  // gemm3 reads cols < this
    for (int j = tid; j < jmax; j += 256) {
        float v = (j < n) ? __expf(row[j] - M) * inv : 0.f;
        arow[j] = (f16)v;
    }
}

// ---------------------------------------------------------------------------
extern "C" void kernel_launch(void* const* d_in, const int* in_sizes, int n_in,
                              void* d_out, int out_size, void* d_ws, size_t ws_size,
                              hipStream_t stream) {
    (void)in_sizes; (void)n_in; (void)out_size; (void)ws_size;
    const float* x = (const float*)d_in[0];
    const float* wqk = (const float*)d_in[1];
    const float* wov = (const float*)d_in[2];
    float* out = (float*)d_out;
    char* ws = (char*)d_ws;
    const size_t MB = 1024 * 1024;

    f16* x_hi    = (f16*)(ws + 0 * MB);    // 8 MB  [T][D]
    f16* x_lo    = (f16*)(ws + 8 * MB);    // 8 MB
    f16* wqkT_hi = (f16*)(ws + 16 * MB);   // 2 MB  [D][D] (= Wqk^T)
    f16* wqkT_lo = (f16*)(ws + 18 * MB);   // 2 MB
    f16* wovT_hi = (f16*)(ws + 20 * MB);   // 2 MB
    f16* wovT_lo = (f16*)(ws + 22 * MB);   // 2 MB
    f16* xT_hi   = (f16*)(ws + 24 * MB);   // 8 MB  [D][T]
    f16* xT_lo   = (f16*)(ws + 32 * MB);   // 8 MB (unused downstream)
    f16* q_hi    = (f16*)(ws + 40 * MB);   // 8 MB  [T][D]
    f16* q_lo    = (f16*)(ws + 48 * MB);   // 8 MB
    f16* z_hi    = (f16*)(ws + 56 * MB);   // 8 MB  [T][D]
    f16* attn    = (f16*)(ws + 64 * MB);   // 32 MB [T][T]
    float* logit = (float*)(ws + 96 * MB); // 64 MB [T][T]
    // total: 160 MB

    // 1) splits / transposes
    split4<<<(T_DIM * D_DIM) / 1024, 256, 0, stream>>>(x, x_hi, x_lo);
    transpose_split<<<dim3(D_DIM / 32, D_DIM / 32), 256, 0, stream>>>(
        wqk, wqkT_hi, wqkT_lo, D_DIM, D_DIM);
    transpose_split<<<dim3(D_DIM / 32, D_DIM / 32), 256, 0, stream>>>(
        wov, wovT_hi, wovT_lo, D_DIM, D_DIM);
    transpose_split<<<dim3(D_DIM / 32, T_DIM / 32), 256, 0, stream>>>(
        x, xT_hi, xT_lo, T_DIM, D_DIM);

    // 2) Q = x @ Wqk  (3-pass split in, fp16 hi/lo out), 128x64, LPS=6
    gemm_nt<128, 64, true, 1, false, false, false>
        <<<dim3(D_DIM / 64, T_DIM / 128), 256, 0, stream>>>(
            x_hi, x_lo, wqkT_hi, wqkT_lo, nullptr, q_hi, q_lo, T_DIM, D_DIM, D_DIM);

    // 3) logits = Q @ x^T  (3-pass split, fp32 out, causal skip), 128x128, LPS=8
    gemm_nt<128, 128, true, 0, true, false, false>
        <<<dim3(T_DIM / 128, T_DIM / 128), 256, 0, stream>>>(
            q_hi, q_lo, x_hi, x_lo, logit, nullptr, nullptr, T_DIM, T_DIM, D_DIM);

    // 4) attn = causal softmax(logits)
    softmax_causal<<<T_DIM, 256, 0, stream>>>(logit, attn);

    // 5) z = attn @ x  (single-pass fp16, K capped at diagonal), 128x64, LPS=3
    gemm_nt<128, 64, false, 2, false, true, true>
        <<<dim3(D_DIM / 64, T_DIM / 128), 256, 0, stream>>>(
            attn, nullptr, xT_hi, nullptr, nullptr, z_hi, nullptr, T_DIM, D_DIM, T_DIM);

    // 6) out = z @ Wov  (single-pass fp16, fp32 out), 128x64, LPS=3
    gemm_nt<128, 64, false, 0, false, false, false>
        <<<dim3(D_DIM / 64, T_DIM / 128), 256, 0, stream>>>(
            z_hi, nullptr, wovT_hi, nullptr, out, nullptr, nullptr, T_DIM, D_DIM, D_DIM);
}

// Round 13
// 280.236 us; speedup vs baseline: 1.2761x; 1.0126x over previous
//
#include <hip/hip_runtime.h>
#include <hip/hip_fp16.h>

#define T_DIM 4096
#define D_DIM 1024

typedef _Float16 f16;
typedef _Float16 f16x4 __attribute__((ext_vector_type(4)));
typedef _Float16 f16x8 __attribute__((ext_vector_type(8)));
typedef float f32x4 __attribute__((ext_vector_type(4)));

#define GAS __attribute__((address_space(1)))
#define LAS __attribute__((address_space(3)))

// ---------------------------------------------------------------------------
// Preprocessing: fp32 -> fp16 hi/lo split (flat, vectorized x4)
// ---------------------------------------------------------------------------
__global__ void split4(const float* __restrict__ in, f16* __restrict__ hi,
                       f16* __restrict__ lo) {
    int i = (blockIdx.x * 256 + threadIdx.x) * 4;
    float4 v = *(const float4*)(in + i);
    float vv[4] = {v.x, v.y, v.z, v.w};
    f16x4 h, l;
#pragma unroll
    for (int j = 0; j < 4; ++j) {
        f16 hh = (f16)vv[j];
        h[j] = hh;
        l[j] = (f16)(vv[j] - (float)hh);
    }
    *(f16x4*)(hi + i) = h;
    *(f16x4*)(lo + i) = l;
}

// ---------------------------------------------------------------------------
// Preprocessing: transpose + split.  in [R][C] fp32 -> hi/lo [C][R] fp16
// ---------------------------------------------------------------------------
__global__ void transpose_split(const float* __restrict__ in, f16* __restrict__ hi,
                                f16* __restrict__ lo, int R, int C) {
    __shared__ float t[32][33];
    int tx = threadIdx.x & 31;
    int ty = threadIdx.x >> 5;  // 0..7
#pragma unroll
    for (int q = 0; q < 4; ++q) {
        int r = blockIdx.y * 32 + ty + q * 8;
        int c = blockIdx.x * 32 + tx;
        t[ty + q * 8][tx] = in[(size_t)r * C + c];
    }
    __syncthreads();
#pragma unroll
    for (int q = 0; q < 4; ++q) {
        int c = blockIdx.x * 32 + ty + q * 8;  // output row (= original col)
        int r = blockIdx.y * 32 + tx;          // output col (= original row)
        float v = t[tx][ty + q * 8];
        size_t idx = (size_t)c * R + r;
        f16 h = (f16)v;
        hi[idx] = h;
        lo[idx] = (f16)(v - (float)h);
    }
}

// ---------------------------------------------------------------------------
// Stage a ROWSx32 fp16 tile (row-major, ld = K) into LDS via global_load_lds.
// LDS layout: ROWS*4 slots of 16B; slot p = r*4 + c'' where the data is global
// chunk c = c'' ^ ((r>>1)&3)  (XOR swizzle applied on the GLOBAL source so the
// LDS destination stays linear — global_load_lds requirement).
// 256 threads; ROWS*4/256 loads per thread; LDS dest is wave-uniform base.
// ---------------------------------------------------------------------------
template <int ROWS>
__device__ __forceinline__ void stage_tile(const f16* __restrict__ src, int ld,
                                           f16* lds_tile, int w, int l) {
    constexpr int ITER = (ROWS * 4) / 256;
#pragma unroll
    for (int q = 0; q < ITER; ++q) {
        int p = q * 256 + w * 64 + l;           // slot id
        int r = p >> 2;                         // tile row
        int c = (p & 3) ^ ((r >> 1) & 3);       // swizzled global 16B chunk
        const f16* g = src + r * ld + c * 8;
        f16* d = lds_tile + (q * 256 + w * 64) * 8;  // wave-uniform base
        __builtin_amdgcn_global_load_lds((const GAS void*)g, (LAS void*)d, 16, 0, 0);
    }
}

// Counted vmcnt wait — immediate must be a literal, so if-constexpr dispatch.
template <int N>
__device__ __forceinline__ void vm_wait() {
    static_assert(N == 0 || N == 3 || N == 6 || N == 8, "unsupported vmcnt");
    if constexpr (N == 0) asm volatile("s_waitcnt vmcnt(0)" ::: "memory");
    else if constexpr (N == 3) asm volatile("s_waitcnt vmcnt(3)" ::: "memory");
    else if constexpr (N == 6) asm volatile("s_waitcnt vmcnt(6)" ::: "memory");
    else if constexpr (N == 8) asm volatile("s_waitcnt vmcnt(8)" ::: "memory");
}

// ---------------------------------------------------------------------------
// Generic NT GEMM: C[M,N] = A[M,K] * B'[N,K]^T   (both operands fp16)
// TM x TN block tile, BK=32, 256 threads = 4 waves in 2x2; wave tile
// (TM/2)x(TN/2); M_REP=TM/32, N_REP=TN/32 fragments of 16x16.
// SPLIT3: A,B given as hi/lo pairs; 3-pass MFMA for ~fp32 product accuracy.
// OUT_MODE: 0 = fp32 C, 1 = fp16 hi/lo split C, 2 = fp16 C.
// CAUSAL_SKIP: skip blocks strictly above the diagonal.
// KCAP_CAUSAL: cap K at row0+TM (A cols beyond are zero).
// REVY: reverse blockIdx.y so longest-K blocks dispatch first (KCAP balance).
//
// 3-buffer rotation, ONE barrier per K-step (no lgkmcnt(0), no 2nd barrier):
//   prologue: stage tile0 -> buf0, tile1 -> buf1      (2*LPS loads in flight)
//   step i:   vmcnt(LPS)          // tile i resident; tile i+1 still flying
//             s_barrier           // B1: whole tile i visible to all waves
//             ds_read frags from buf[i%3]
//             stage tile i+2 -> buf[(i+2)%3]   // nobody reads this buf now;
//                                              // (i+2)%3 == (i-1)%3, whose
//                                              // readers all passed B1(i)
//             MFMA   (compiler interleaves fine-grained lgkmcnt waits)
//   last step waits vmcnt(0) (peeled via conditional).
// Safety: wave reaches B1(i) only after step i-1 MFMAs issued => its
// buf[(i-1)%3] ds_reads completed; barrier => true for ALL waves => staging
// into buf[(i-1)%3] during step i cannot race any read.
// ---------------------------------------------------------------------------
template <int TM, int TN, bool SPLIT3, int OUT_MODE, bool CAUSAL_SKIP,
          bool KCAP_CAUSAL, bool REVY>
__global__ __launch_bounds__(256) void gemm_nt(
    const f16* __restrict__ Ah, const f16* __restrict__ Al,
    const f16* __restrict__ Bh, const f16* __restrict__ Bl,
    float* __restrict__ Cf, f16* __restrict__ Ch, f16* __restrict__ Cl,
    int M, int N, int K) {
    const int by = REVY ? (gridDim.y - 1 - blockIdx.y) : blockIdx.y;
    const int row0 = by * TM;
    const int col0 = blockIdx.x * TN;
    if (CAUSAL_SKIP) {
        if (col0 > row0 + TM - 1) return;  // wholly above diagonal: never read
    }
    int Keff = K;
    if (KCAP_CAUSAL) {
        Keff = row0 + TM;
        if (Keff > K) Keff = K;
    }

    constexpr int TILE_A = TM * 32;           // f16 elems per A tile
    constexpr int TILE_B = TN * 32;
    constexpr int BUFSZ = (SPLIT3 ? 2 : 1) * (TILE_A + TILE_B);
    constexpr int M_REP = TM / 32;
    constexpr int N_REP = TN / 32;
    // loads per stage_all per thread (16B each): vmcnt bookkeeping constant
    constexpr int LPS = (SPLIT3 ? 2 : 1) * (TM + TN) / 64;
    __shared__ f16 lds[3 * BUFSZ];            // triple buffer

    const int tid = threadIdx.x;
    const int w = tid >> 6, l = tid & 63;
    const int wm = w >> 1, wn = w & 1;
    const int lr = l & 15;   // row within 16x16 fragment
    const int kg = l >> 4;   // k-group (8 consecutive k per group)
    const int cswz = kg ^ ((lr >> 1) & 3);
    // (row>>1)&3 == (lr>>1)&3 for all frag rows: wave/frag offsets are =0 mod 32
    const int aoff = (wm * (TM / 2) + lr) * 32 + cswz * 8;
    const int boff = (wn * (TN / 2) + lr) * 32 + cswz * 8;

    const f16* Asrc = Ah + (size_t)row0 * K;
    const f16* Bsrc = Bh + (size_t)col0 * K;
    const f16* Asrc_l = SPLIT3 ? Al + (size_t)row0 * K : nullptr;
    const f16* Bsrc_l = SPLIT3 ? Bl + (size_t)col0 * K : nullptr;

    auto stage_all = [&](int buf, int k0) {
        f16* base = lds + buf * BUFSZ;
        stage_tile<TM>(Asrc + k0, K, base, w, l);
        stage_tile<TN>(Bsrc + k0, K, base + TILE_A, w, l);
        if constexpr (SPLIT3) {
            stage_tile<TM>(Asrc_l + k0, K, base + TILE_A + TILE_B, w, l);
            stage_tile<TN>(Bsrc_l + k0, K, base + 2 * TILE_A + TILE_B, w, l);
        }
    };

    f32x4 acc[M_REP][N_REP] = {};

    const int nsteps = Keff >> 5;  // >= 4 for all instantiations

    // prologue: fill buffers 0 and 1 (2*LPS loads in flight, no wait)
    stage_all(0, 0);
    stage_all(1, 32);

    int cur = 0;  // = i % 3
    for (int i = 0; i < nsteps; ++i) {
        // B1: tile i resident (tile i+1's LPS loads may remain in flight)
        if (i + 1 < nsteps) vm_wait<LPS>(); else vm_wait<0>();
        __builtin_amdgcn_sched_barrier(0);
        __builtin_amdgcn_s_barrier();
        __builtin_amdgcn_sched_barrier(0);

        const f16* base = lds + cur * BUFSZ;
        const f16* Ah_t = base;
        const f16* Bh_t = base + TILE_A;
        const f16* Al_t = base + TILE_A + TILE_B;
        const f16* Bl_t = base + 2 * TILE_A + TILE_B;

        f16x8 ah[M_REP], bh[N_REP], al[M_REP], bl[N_REP];
#pragma unroll
        for (int m = 0; m < M_REP; ++m) {
            ah[m] = *(const f16x8*)&Ah_t[aoff + m * 512];
            if constexpr (SPLIT3) al[m] = *(const f16x8*)&Al_t[aoff + m * 512];
        }
#pragma unroll
        for (int n = 0; n < N_REP; ++n) {
            bh[n] = *(const f16x8*)&Bh_t[boff + n * 512];
            if constexpr (SPLIT3) bl[n] = *(const f16x8*)&Bl_t[boff + n * 512];
        }

        // stage tile i+2 into buf[(i+2)%3] == buf[(i-1)%3]: free (see header)
        if (i + 2 < nsteps) {
            const int stg = (cur == 0) ? 2 : cur - 1;
            stage_all(stg, (i + 2) * 32);
        }

#pragma unroll
        for (int m = 0; m < M_REP; ++m)
#pragma unroll
            for (int n = 0; n < N_REP; ++n) {
                acc[m][n] = __builtin_amdgcn_mfma_f32_16x16x32_f16(ah[m], bh[n],
                                                                   acc[m][n], 0, 0, 0);
                if constexpr (SPLIT3) {
                    acc[m][n] = __builtin_amdgcn_mfma_f32_16x16x32_f16(
                        al[m], bh[n], acc[m][n], 0, 0, 0);
                    acc[m][n] = __builtin_amdgcn_mfma_f32_16x16x32_f16(
                        ah[m], bl[n], acc[m][n], 0, 0, 0);
                }
            }

        cur = (cur == 2) ? 0 : cur + 1;
    }

    // Epilogue. C/D layout: col = lane&15, row = (lane>>4)*4 + reg  [m89/m91]
#pragma unroll
    for (int m = 0; m < M_REP; ++m)
#pragma unroll
        for (int n = 0; n < N_REP; ++n)
#pragma unroll
            for (int j = 0; j < 4; ++j) {
                int row = row0 + wm * (TM / 2) + m * 16 + kg * 4 + j;
                int col = col0 + wn * (TN / 2) + n * 16 + lr;
                size_t idx = (size_t)row * N + col;
                float v = acc[m][n][j];
                if constexpr (OUT_MODE == 0) {
                    Cf[idx] = v;
                } else if constexpr (OUT_MODE == 1) {
                    f16 h = (f16)v;
                    Ch[idx] = h;
                    Cl[idx] = (f16)(v - (float)h);
                } else {
                    Ch[idx] = (f16)v;
                }
            }
}

// ---------------------------------------------------------------------------
// Causal row softmax: logits [T,T] fp32 -> attn [T,T] fp16.
// Row i uses cols 0..i; writes zeros for i < j < jmax (next 128 boundary,
// which is all the z-GEMM will ever read).
// ---------------------------------------------------------------------------
__global__ void softmax_causal(const float* __restrict__ L, f16* __restrict__ A) {
    const int i = blockIdx.x;
    const int n = i + 1;
    const int tid = threadIdx.x;  // 256 threads
    const float* row = L + (size_t)i * T_DIM;
    f16* arow = A + (size_t)i * T_DIM;

    float m = -INFINITY, s = 0.f;
    for (int j = tid; j < n; j += 256) {
        float v = row[j];
        if (v > m) {
            s = s * __expf(m - v) + 1.f;
            m = v;
        } else {
            s += __expf(v - m);
        }
    }

    __shared__ float sm[256], ss[256];
    sm[tid] = m;
    ss[tid] = s;
    __syncthreads();
    for (int o = 128; o > 0; o >>= 1) {
        if (tid < o) {
            float m1 = sm[tid], s1 = ss[tid];
            float m2 = sm[tid + o], s2 = ss[tid + o];
            float M = fmaxf(m1, m2);
            float S = (M == -INFINITY) ? 0.f
                                       : s1 * __expf(m1 - M) + s2 * __expf(m2 - M);
            sm[tid] = M;
            ss[tid] = S;
        }
        __syncthreads();
    }
    const float M = sm[0];
    const float inv = 1.f / ss[0];

    const int jmax = ((i >> 7) + 1) << 7;  // z-GEMM reads cols < this
    for (int j = tid; j < jmax; j += 256) {
        float v = (j < n) ? __expf(row[j] - M) * inv : 0.f;
        arow[j] = (f16)v;
    }
}

// ---------------------------------------------------------------------------
extern "C" void kernel_launch(void* const* d_in, const int* in_sizes, int n_in,
                              void* d_out, int out_size, void* d_ws, size_t ws_size,
                              hipStream_t stream) {
    (void)in_sizes; (void)n_in; (void)out_size; (void)ws_size;
    const float* x = (const float*)d_in[0];
    const float* wqk = (const float*)d_in[1];
    const float* wov = (const float*)d_in[2];
    float* out = (float*)d_out;
    char* ws = (char*)d_ws;
    const size_t MB = 1024 * 1024;

    f16* x_hi    = (f16*)(ws + 0 * MB);    // 8 MB  [T][D]
    f16* x_lo    = (f16*)(ws + 8 * MB);    // 8 MB
    f16* wqkT_hi = (f16*)(ws + 16 * MB);   // 2 MB  [D][D] (= Wqk^T)
    f16* wqkT_lo = (f16*)(ws + 18 * MB);   // 2 MB
    f16* wovT_hi = (f16*)(ws + 20 * MB);   // 2 MB
    f16* wovT_lo = (f16*)(ws + 22 * MB);   // 2 MB
    f16* xT_hi   = (f16*)(ws + 24 * MB);   // 8 MB  [D][T]
    f16* xT_lo   = (f16*)(ws + 32 * MB);   // 8 MB (unused downstream)
    f16* q_hi    = (f16*)(ws + 40 * MB);   // 8 MB  [T][D]
    f16* q_lo    = (f16*)(ws + 48 * MB);   // 8 MB
    f16* z_hi    = (f16*)(ws + 56 * MB);   // 8 MB  [T][D]
    f16* attn    = (f16*)(ws + 64 * MB);   // 32 MB [T][T]
    float* logit = (float*)(ws + 96 * MB); // 64 MB [T][T]
    // total: 160 MB

    // 1) splits / transposes
    split4<<<(T_DIM * D_DIM) / 1024, 256, 0, stream>>>(x, x_hi, x_lo);
    transpose_split<<<dim3(D_DIM / 32, D_DIM / 32), 256, 0, stream>>>(
        wqk, wqkT_hi, wqkT_lo, D_DIM, D_DIM);
    transpose_split<<<dim3(D_DIM / 32, D_DIM / 32), 256, 0, stream>>>(
        wov, wovT_hi, wovT_lo, D_DIM, D_DIM);
    transpose_split<<<dim3(D_DIM / 32, T_DIM / 32), 256, 0, stream>>>(
        x, xT_hi, xT_lo, T_DIM, D_DIM);

    // 2) Q = x @ Wqk  (3-pass split in, fp16 hi/lo out), 128x64, LPS=6,
    //    3-buf 72KB -> 2 blocks/CU, 512 blocks = exactly 2 rounds
    gemm_nt<128, 64, true, 1, false, false, false>
        <<<dim3(D_DIM / 64, T_DIM / 128), 256, 0, stream>>>(
            x_hi, x_lo, wqkT_hi, wqkT_lo, nullptr, q_hi, q_lo, T_DIM, D_DIM, D_DIM);

    // 3) logits = Q @ x^T  (3-pass split, fp32 out, causal skip)
    //    128x64: 1056 live blocks (thin tail), 3-buf 72KB -> 2 blocks/CU
    gemm_nt<128, 64, true, 0, true, false, false>
        <<<dim3(T_DIM / 64, T_DIM / 128), 256, 0, stream>>>(
            q_hi, q_lo, x_hi, x_lo, logit, nullptr, nullptr, T_DIM, T_DIM, D_DIM);

    // 4) attn = causal softmax(logits)
    softmax_causal<<<T_DIM, 256, 0, stream>>>(logit, attn);

    // 5) z = attn @ x  (single-pass fp16, K capped at diagonal), 128x64, LPS=3
    gemm_nt<128, 64, false, 2, false, true, true>
        <<<dim3(D_DIM / 64, T_DIM / 128), 256, 0, stream>>>(
            attn, nullptr, xT_hi, nullptr, nullptr, z_hi, nullptr, T_DIM, D_DIM, T_DIM);

    // 6) out = z @ Wov  (single-pass fp16, fp32 out), 128x64, LPS=3
    gemm_nt<128, 64, false, 0, false, false, false>
        <<<dim3(D_DIM / 64, T_DIM / 128), 256, 0, stream>>>(
            z_hi, nullptr, wovT_hi, nullptr, out, nullptr, nullptr, T_DIM, D_DIM, D_DIM);
}

// Round 14
// 270.431 us; speedup vs baseline: 1.3223x; 1.0363x over previous
//
#include <hip/hip_runtime.h>
#include <hip/hip_fp16.h>

#define T_DIM 4096
#define D_DIM 1024

typedef _Float16 f16;
typedef _Float16 f16x4 __attribute__((ext_vector_type(4)));
typedef _Float16 f16x8 __attribute__((ext_vector_type(8)));
typedef float f32x4 __attribute__((ext_vector_type(4)));

#define GAS __attribute__((address_space(1)))
#define LAS __attribute__((address_space(3)))

// ---------------------------------------------------------------------------
// Preprocessing: fp32 -> fp16 hi/lo split (flat, vectorized x4)
// ---------------------------------------------------------------------------
__global__ void split4(const float* __restrict__ in, f16* __restrict__ hi,
                       f16* __restrict__ lo) {
    int i = (blockIdx.x * 256 + threadIdx.x) * 4;
    float4 v = *(const float4*)(in + i);
    float vv[4] = {v.x, v.y, v.z, v.w};
    f16x4 h, l;
#pragma unroll
    for (int j = 0; j < 4; ++j) {
        f16 hh = (f16)vv[j];
        h[j] = hh;
        l[j] = (f16)(vv[j] - (float)hh);
    }
    *(f16x4*)(hi + i) = h;
    *(f16x4*)(lo + i) = l;
}

// ---------------------------------------------------------------------------
// Preprocessing: transpose + split.  in [R][C] fp32 -> hi (and optional lo)
// [C][R] fp16
// ---------------------------------------------------------------------------
__global__ void transpose_split(const float* __restrict__ in, f16* __restrict__ hi,
                                f16* __restrict__ lo, int R, int C) {
    __shared__ float t[32][33];
    int tx = threadIdx.x & 31;
    int ty = threadIdx.x >> 5;  // 0..7
#pragma unroll
    for (int q = 0; q < 4; ++q) {
        int r = blockIdx.y * 32 + ty + q * 8;
        int c = blockIdx.x * 32 + tx;
        t[ty + q * 8][tx] = in[(size_t)r * C + c];
    }
    __syncthreads();
#pragma unroll
    for (int q = 0; q < 4; ++q) {
        int c = blockIdx.x * 32 + ty + q * 8;  // output row (= original col)
        int r = blockIdx.y * 32 + tx;          // output col (= original row)
        float v = t[tx][ty + q * 8];
        size_t idx = (size_t)c * R + r;
        f16 h = (f16)v;
        hi[idx] = h;
        if (lo) lo[idx] = (f16)(v - (float)h);
    }
}

// ---------------------------------------------------------------------------
// Stage a ROWSxBK fp16 tile (row-major, ld = K) into LDS via global_load_lds.
// LDS layout: ROWS*BK/8 slots of 16B, linear; the XOR swizzle is applied on
// the GLOBAL source (global_load_lds needs a linear LDS dest — rule #21).
//   BK=32 (4 chunks/row): c = c0 ^ ((r>>1)&3)
//   BK=64 (8 chunks/row): c = c0 ^ (r&7)
// Both keep per-row sources as one permuted 64/128B segment (coalesced) and
// match the ds_read swizzle below (same involution).
// ---------------------------------------------------------------------------
template <int ROWS, int BK>
__device__ __forceinline__ void stage_tile(const f16* __restrict__ src, int ld,
                                           f16* lds_tile, int w, int l) {
    constexpr int CH = BK / 8;               // 16B chunks per row
    constexpr int ITER = (ROWS * BK) / 2048; // per-thread loads
#pragma unroll
    for (int q = 0; q < ITER; ++q) {
        int p = q * 256 + w * 64 + l;        // slot id
        int r = p / CH;                      // tile row
        int c0 = p % CH;
        int c = (BK == 32) ? (c0 ^ ((r >> 1) & 3)) : (c0 ^ (r & 7));
        const f16* g = src + r * ld + c * 8;
        f16* d = lds_tile + (q * 256 + w * 64) * 8;  // wave-uniform base
        __builtin_amdgcn_global_load_lds((const GAS void*)g, (LAS void*)d, 16, 0, 0);
    }
}

// Counted vmcnt wait — immediate must be a literal, so if-constexpr dispatch.
template <int N>
__device__ __forceinline__ void vm_wait() {
    static_assert(N == 0 || N == 3 || N == 6 || N == 8, "unsupported vmcnt");
    if constexpr (N == 0) asm volatile("s_waitcnt vmcnt(0)" ::: "memory");
    else if constexpr (N == 3) asm volatile("s_waitcnt vmcnt(3)" ::: "memory");
    else if constexpr (N == 6) asm volatile("s_waitcnt vmcnt(6)" ::: "memory");
    else if constexpr (N == 8) asm volatile("s_waitcnt vmcnt(8)" ::: "memory");
}

// ---------------------------------------------------------------------------
// Generic NT GEMM: C[M,N] = A[M,K] * B'[N,K]^T   (both operands fp16)
// TM x TN block tile, BK per K-step, 256 threads = 4 waves in 2x2.
// SPLIT3: A,B given as hi/lo pairs; 3-pass MFMA for ~fp32 product accuracy.
// OUT_MODE: 0 = fp32 C, 1 = fp16 hi/lo split C, 2 = fp16 C.
// CAUSAL_SKIP / KCAP_CAUSAL / REVY: causal-triangle helpers.
//
// NBUF=2 (round-11 schedule, measured 90.0us on logits 128x128):
//   step i: vmcnt(LPS); barrier; ds_read all frags; lgkmcnt(0); barrier;
//           stage tile i+2 -> buf[cur]; MFMA; cur^=1.
// NBUF=3 (round-13 schedule, single barrier):
//   step i: vmcnt(LPS); barrier; {per kk: ds_read frags; [kk=0: stage tile
//           i+2 -> buf[(i+2)%3]]; MFMA}; cur=(cur+1)%3.
//   Safety: readers of buf[(i-1)%3] all passed B1(i) before the stage.
// ---------------------------------------------------------------------------
template <int TM, int TN, int BK, int NBUF, bool SPLIT3, int OUT_MODE,
          bool CAUSAL_SKIP, bool KCAP_CAUSAL, bool REVY>
__global__ __launch_bounds__(256) void gemm_nt(
    const f16* __restrict__ Ah, const f16* __restrict__ Al,
    const f16* __restrict__ Bh, const f16* __restrict__ Bl,
    float* __restrict__ Cf, f16* __restrict__ Ch, f16* __restrict__ Cl,
    int M, int N, int K) {
    static_assert(NBUF == 3 || BK == 32, "NBUF=2 schedule assumes BK=32");
    const int by = REVY ? (gridDim.y - 1 - blockIdx.y) : blockIdx.y;
    const int row0 = by * TM;
    const int col0 = blockIdx.x * TN;
    if (CAUSAL_SKIP) {
        if (col0 > row0 + TM - 1) return;  // wholly above diagonal: never read
    }
    int Keff = K;
    if (KCAP_CAUSAL) {
        Keff = row0 + TM;
        if (Keff > K) Keff = K;
    }

    constexpr int TILE_A = TM * BK;           // f16 elems per A tile
    constexpr int TILE_B = TN * BK;
    constexpr int BUFSZ = (SPLIT3 ? 2 : 1) * (TILE_A + TILE_B);
    constexpr int M_REP = TM / 32;
    constexpr int N_REP = TN / 32;
    // loads per stage_all per thread (16B each): vmcnt bookkeeping constant
    constexpr int LPS = (SPLIT3 ? 2 : 1) * (TM + TN) * BK / 2048;
    __shared__ f16 lds[NBUF * BUFSZ];

    const int tid = threadIdx.x;
    const int w = tid >> 6, l = tid & 63;
    const int wm = w >> 1, wn = w & 1;
    const int lr = l & 15;   // row within 16x16 fragment
    const int kg = l >> 4;   // k-group (8 consecutive k per group)
    const int arow = (wm * (TM / 2) + lr) * BK;
    const int brow = (wn * (TN / 2) + lr) * BK;

    const f16* Asrc = Ah + (size_t)row0 * K;
    const f16* Bsrc = Bh + (size_t)col0 * K;
    const f16* Asrc_l = SPLIT3 ? Al + (size_t)row0 * K : nullptr;
    const f16* Bsrc_l = SPLIT3 ? Bl + (size_t)col0 * K : nullptr;

    auto stage_all = [&](int buf, int k0) {
        f16* base = lds + buf * BUFSZ;
        stage_tile<TM, BK>(Asrc + k0, K, base, w, l);
        stage_tile<TN, BK>(Bsrc + k0, K, base + TILE_A, w, l);
        if constexpr (SPLIT3) {
            stage_tile<TM, BK>(Asrc_l + k0, K, base + TILE_A + TILE_B, w, l);
            stage_tile<TN, BK>(Bsrc_l + k0, K, base + 2 * TILE_A + TILE_B, w, l);
        }
    };

    f32x4 acc[M_REP][N_REP] = {};

    const int nsteps = Keff / BK;  // >= 2 for all instantiations

    // prologue: fill buffers 0 and 1 (2*LPS loads in flight, no wait)
    stage_all(0, 0);
    stage_all(1, BK);

    int cur = 0;
    for (int i = 0; i < nsteps; ++i) {
        // B1: tile i resident (tile i+1's LPS loads may remain in flight)
        if (i + 1 < nsteps) vm_wait<LPS>(); else vm_wait<0>();
        __builtin_amdgcn_sched_barrier(0);
        __builtin_amdgcn_s_barrier();
        __builtin_amdgcn_sched_barrier(0);

        const f16* base = lds + cur * BUFSZ;
        const f16* Ah_t = base;
        const f16* Bh_t = base + TILE_A;
        const f16* Al_t = base + TILE_A + TILE_B;
        const f16* Bl_t = base + 2 * TILE_A + TILE_B;

#pragma unroll
        for (int kk = 0; kk < BK / 32; ++kk) {
            // swizzled chunk index for this k-substep (matches stage swizzle)
            const int chA = (BK == 32) ? (kg ^ ((lr >> 1) & 3))
                                       : ((kk * 4 + kg) ^ (lr & 7));
            const int aoff = arow + chA * 8;
            const int boff = brow + chA * 8;

            f16x8 ah[M_REP], bh[N_REP], al[M_REP], bl[N_REP];
#pragma unroll
            for (int m = 0; m < M_REP; ++m) {
                ah[m] = *(const f16x8*)&Ah_t[aoff + m * 16 * BK];
                if constexpr (SPLIT3) al[m] = *(const f16x8*)&Al_t[aoff + m * 16 * BK];
            }
#pragma unroll
            for (int n = 0; n < N_REP; ++n) {
                bh[n] = *(const f16x8*)&Bh_t[boff + n * 16 * BK];
                if constexpr (SPLIT3) bl[n] = *(const f16x8*)&Bl_t[boff + n * 16 * BK];
            }

            if constexpr (NBUF == 2) {
                // B2 (after ALL reads, BK==32 so kk==0 is last): buffer free
                asm volatile("s_waitcnt lgkmcnt(0)" ::: "memory");
                __builtin_amdgcn_sched_barrier(0);
                __builtin_amdgcn_s_barrier();
                __builtin_amdgcn_sched_barrier(0);
            }

            if (kk == 0 && i + 2 < nsteps) {
                const int stg = (NBUF == 2) ? cur : ((cur == 0) ? 2 : cur - 1);
                stage_all(stg, (i + 2) * BK);
            }

#pragma unroll
            for (int m = 0; m < M_REP; ++m)
#pragma unroll
                for (int n = 0; n < N_REP; ++n) {
                    acc[m][n] = __builtin_amdgcn_mfma_f32_16x16x32_f16(
                        ah[m], bh[n], acc[m][n], 0, 0, 0);
                    if constexpr (SPLIT3) {
                        acc[m][n] = __builtin_amdgcn_mfma_f32_16x16x32_f16(
                            al[m], bh[n], acc[m][n], 0, 0, 0);
                        acc[m][n] = __builtin_amdgcn_mfma_f32_16x16x32_f16(
                            ah[m], bl[n], acc[m][n], 0, 0, 0);
                    }
                }
        }

        cur = (cur + 1 == NBUF) ? 0 : cur + 1;
    }

    // Epilogue. C/D layout: col = lane&15, row = (lane>>4)*4 + reg  [m89/m91]
#pragma unroll
    for (int m = 0; m < M_REP; ++m)
#pragma unroll
        for (int n = 0; n < N_REP; ++n)
#pragma unroll
            for (int j = 0; j < 4; ++j) {
                int row = row0 + wm * (TM / 2) + m * 16 + kg * 4 + j;
                int col = col0 + wn * (TN / 2) + n * 16 + lr;
                size_t idx = (size_t)row * N + col;
                float v = acc[m][n][j];
                if constexpr (OUT_MODE == 0) {
                    Cf[idx] = v;
                } else if constexpr (OUT_MODE == 1) {
                    f16 h = (f16)v;
                    Ch[idx] = h;
                    Cl[idx] = (f16)(v - (float)h);
                } else {
                    Ch[idx] = (f16)v;
                }
            }
}

// ---------------------------------------------------------------------------
// Causal row softmax: logits [T,T] fp32 -> attn [T,T] fp16.
// Row i uses cols 0..i; writes zeros for i < j < jmax (next 128 boundary,
// which is all the z-GEMM will ever read).
// ---------------------------------------------------------------------------
__global__ void softmax_causal(const float* __restrict__ L, f16* __restrict__ A) {
    const int i = blockIdx.x;
    const int n = i + 1;
    const int tid = threadIdx.x;  // 256 threads
    const float* row = L + (size_t)i * T_DIM;
    f16* arow = A + (size_t)i * T_DIM;

    float m = -INFINITY, s = 0.f;
    for (int j = tid; j < n; j += 256) {
        float v = row[j];
        if (v > m) {
            s = s * __expf(m - v) + 1.f;
            m = v;
        } else {
            s += __expf(v - m);
        }
    }

    __shared__ float sm[256], ss[256];
    sm[tid] = m;
    ss[tid] = s;
    __syncthreads();
    for (int o = 128; o > 0; o >>= 1) {
        if (tid < o) {
            float m1 = sm[tid], s1 = ss[tid];
            float m2 = sm[tid + o], s2 = ss[tid + o];
            float M = fmaxf(m1, m2);
            float S = (M == -INFINITY) ? 0.f
                                       : s1 * __expf(m1 - M) + s2 * __expf(m2 - M);
            sm[tid] = M;
            ss[tid] = S;
        }
        __syncthreads();
    }
    const float M = sm[0];
    const float inv = 1.f / ss[0];

    const int jmax = ((i >> 7) + 1) << 7;  // z-GEMM reads cols < this
    for (int j = tid; j < jmax; j += 256) {
        float v = (j < n) ? __expf(row[j] - M) * inv : 0.f;
        arow[j] = (f16)v;
    }
}

// ---------------------------------------------------------------------------
extern "C" void kernel_launch(void* const* d_in, const int* in_sizes, int n_in,
                              void* d_out, int out_size, void* d_ws, size_t ws_size,
                              hipStream_t stream) {
    (void)in_sizes; (void)n_in; (void)out_size; (void)ws_size;
    const float* x = (const float*)d_in[0];
    const float* wqk = (const float*)d_in[1];
    const float* wov = (const float*)d_in[2];
    float* out = (float*)d_out;
    char* ws = (char*)d_ws;
    const size_t MB = 1024 * 1024;

    f16* x_hi    = (f16*)(ws + 0 * MB);    // 8 MB  [T][D]
    f16* x_lo    = (f16*)(ws + 8 * MB);    // 8 MB
    f16* wqkT_hi = (f16*)(ws + 16 * MB);   // 2 MB  [D][D] (= Wqk^T)
    f16* wqkT_lo = (f16*)(ws + 18 * MB);   // 2 MB
    f16* wovT_hi = (f16*)(ws + 20 * MB);   // 2 MB
    f16* wovT_lo = (f16*)(ws + 22 * MB);   // 2 MB
    f16* xT_hi   = (f16*)(ws + 24 * MB);   // 8 MB  [D][T]
    f16* q_hi    = (f16*)(ws + 40 * MB);   // 8 MB  [T][D]
    f16* q_lo    = (f16*)(ws + 48 * MB);   // 8 MB
    f16* z_hi    = (f16*)(ws + 56 * MB);   // 8 MB  [T][D]
    f16* attn    = (f16*)(ws + 64 * MB);   // 32 MB [T][T]
    float* logit = (float*)(ws + 96 * MB); // 64 MB [T][T]
    // total: 160 MB

    // 1) splits / transposes (xT needs hi only — z-GEMM is single-pass)
    split4<<<(T_DIM * D_DIM) / 1024, 256, 0, stream>>>(x, x_hi, x_lo);
    transpose_split<<<dim3(D_DIM / 32, D_DIM / 32), 256, 0, stream>>>(
        wqk, wqkT_hi, wqkT_lo, D_DIM, D_DIM);
    transpose_split<<<dim3(D_DIM / 32, D_DIM / 32), 256, 0, stream>>>(
        wov, wovT_hi, wovT_lo, D_DIM, D_DIM);
    transpose_split<<<dim3(D_DIM / 32, T_DIM / 32), 256, 0, stream>>>(
        x, xT_hi, nullptr, T_DIM, D_DIM);

    // 2) Q = x @ Wqk  (3-pass split in, fp16 hi/lo out)
    //    128x64, BK=32, 3-buf (72KB, 2 blocks/CU), LPS=6 — round-13 config
    gemm_nt<128, 64, 32, 3, true, 1, false, false, false>
        <<<dim3(D_DIM / 64, T_DIM / 128), 256, 0, stream>>>(
            x_hi, x_lo, wqkT_hi, wqkT_lo, nullptr, q_hi, q_lo, T_DIM, D_DIM, D_DIM);

    // 3) logits = Q @ x^T  (3-pass split, fp32 out, causal skip)
    //    128x128, BK=32, 2-buf counted (64KB, 2 blocks/CU), LPS=8 —
    //    round-11 measured-best config (90.0us)
    gemm_nt<128, 128, 32, 2, true, 0, true, false, false>
        <<<dim3(T_DIM / 128, T_DIM / 128), 256, 0, stream>>>(
            q_hi, q_lo, x_hi, x_lo, logit, nullptr, nullptr, T_DIM, T_DIM, D_DIM);

    // 4) attn = causal softmax(logits)
    softmax_causal<<<T_DIM, 256, 0, stream>>>(logit, attn);

    // 5) z = attn @ x  (single-pass fp16, K capped at diagonal)
    //    128x64, BK=64 (halved step count), 3-buf 72KB, LPS=6, REVY
    gemm_nt<128, 64, 64, 3, false, 2, false, true, true>
        <<<dim3(D_DIM / 64, T_DIM / 128), 256, 0, stream>>>(
            attn, nullptr, xT_hi, nullptr, nullptr, z_hi, nullptr, T_DIM, D_DIM, T_DIM);

    // 6) out = z @ Wov  (single-pass fp16, fp32 out), 128x64, BK=64, LPS=6
    gemm_nt<128, 64, 64, 3, false, 0, false, false, false>
        <<<dim3(D_DIM / 64, T_DIM / 128), 256, 0, stream>>>(
            z_hi, nullptr, wovT_hi, nullptr, out, nullptr, nullptr, T_DIM, D_DIM, D_DIM);
}